// Round 3
// baseline (198.767 us; speedup 1.0000x reference)
//
#include <hip/hip_runtime.h>
#include <stdint.h>

typedef unsigned int u32;
typedef unsigned long long u64;

#define N8   130560   // (2176/8)*(3840/8)   = 272*480
#define N16  32640    // (2176/16)*(3840/16) = 136*240
#define N32  8160     // (2176/32)*(3840/32) = 68*120
#define NTOT 171360
#define NTOT4 42840   // NTOT/4
#define TOPK 1000
#define NWORDS 16
#define NBINS 4096
#define BUCKET_SCALE 682.0f
#define LIST_CAP 2048
#define NBLK 168           // ceil(NTOT4/256); <=256 CUs -> co-resident (required for spins)
#define NRED 32            // reducer blocks
#define RANK_BLKS 32       // rank blocks (64 candidates each)
#define IOU_TASKS (TOPK * NWORDS)   // 16000
#define IOU_BLKS 63
#define NMS_CACHE 256
#define POISON 0xAAAAAAAAu
#define SPIN_CAP (1u << 22)   // ~0.5s safety valve: converts any deadlock into a
                              // completed-but-wrong run (diagnosable) instead of a
                              // hung queue -> dead container (info-free)

// R11: fix compile error (s_sleep needs a CONSTANT int -> spin_tag is now a
// template<int SLP>). This also explains R9's "container failed twice": same
// compile failure, different surfacing. The fused design has never run until now.
// Structure unchanged from R9/R10: K0(meta zero) + k_fused (hist -> reduce ->
// findB -> compact -> rank+decode -> IOU -> NMS), validated sc1 + syncthreads-
// drain + arrive-RMW + 0xC0DE-tag handoffs, poison-tolerant counters, self-
// cleaning sync vars, all `out` writes sc1.

// meta u32 indices — ONE sync variable per 512 B line
#define MI_ARRA 0      // phase A arrive ctr (RMW-only)
#define MI_REDA 128    // partials-ready flag
#define MI_ARRB 256    // reduce arrive ctr
#define MI_REDD 384    // reduced-ready flag
#define MI_B    512    // B publish: 0xC0DE0000 | B
#define MI_CNT  640    // list count atomic (RMW-only line)
#define MI_CMP  768    // compact arrive ctr
#define MI_CMPD 896    // compact done flag: 0xC0DE0000 | cnt
#define MI_DEC  1024   // decode arrive ctr
#define MI_DECD 1152   // decode done flag: 0xC0DE0000 | cnt
#define MI_IOU  1280   // iou arrive ctr
#define META_U32 1536  // 6 KB

// workspace layout (bytes)
#define OFF_PART 0                  // u32[168*2048] packed u16-pair partial hist
#define OFF_RED  1376256            // u32[4096]
#define OFF_META 1392640            // u32[1536]
#define OFF_NZ   1398784            // u64[16]
#define OFF_LIST 1398912            // u64[2048]
#define OFF_MASK 1415296            // u64[16*1000], transposed: mask[w*1000+i]

__device__ __forceinline__ u32 ald32(const u32* p) {
  return __hip_atomic_load(p, __ATOMIC_RELAXED, __HIP_MEMORY_SCOPE_AGENT);
}
__device__ __forceinline__ u64 ald64(const u64* p) {
  return __hip_atomic_load(p, __ATOMIC_RELAXED, __HIP_MEMORY_SCOPE_AGENT);
}
__device__ __forceinline__ void ast32(u32* p, u32 v) {
  __hip_atomic_store(p, v, __ATOMIC_RELAXED, __HIP_MEMORY_SCOPE_AGENT);
}
__device__ __forceinline__ void ast64(u64* p, u64 v) {
  __hip_atomic_store(p, v, __ATOMIC_RELAXED, __HIP_MEMORY_SCOPE_AGENT);
}
__device__ __forceinline__ void publish(u32* p, u32 v) {
  __hip_atomic_store(p, v, __ATOMIC_RELEASE, __HIP_MEMORY_SCOPE_AGENT);
}
template <int SLP>
__device__ __forceinline__ u32 spin_tag(const u32* p) {
  u32 v, it = 0;
  while (((v = ald32(p)) >> 16) != 0xC0DEu) {
    __builtin_amdgcn_s_sleep(SLP);   // SLP is a compile-time constant (gfx950 req)
    if (++it > SPIN_CAP) break;      // never triggers when healthy (<100us kernel)
  }
  return v;
}
__device__ __forceinline__ u32 normc(u32 v) {   // tolerate 0xAAAAAAAA poison base
  return v >= 0x80000000u ? v - POISON : v;
}
// returns true for the LAST arriver; self-resets the counter for the next launch
__device__ __forceinline__ bool arrive_last(u32* p, u32 total) {
  u32 old = __hip_atomic_fetch_add(p, 1u, __ATOMIC_RELAXED, __HIP_MEMORY_SCOPE_AGENT);
  if (normc(old) == total - 1u) { ast32(p, 0u); return true; }
  return false;
}

__device__ __forceinline__ u32 bucket_of(float x) {
  u32 b = (u32)(x * BUCKET_SCALE);
  return b > (NBINS - 1) ? (NBINS - 1) : b;
}

__device__ __forceinline__ float4 load_logit4(int v, const float* s8, const float* s16,
                                              const float* s32) {
  int e = v * 4;
  if (e < N8) return ((const float4*)s8)[v];
  if (e < N8 + N16) return ((const float4*)s16)[v - N8 / 4];
  return ((const float4*)s32)[v - (N8 + N16) / 4];
}

__device__ __forceinline__ bool iou_gt04(float4 a, float4 b) {
#pragma clang fp contract(off)
  float areaA = (a.z - a.x) * (a.w - a.y);
  float areaB = (b.z - b.x) * (b.w - b.y);
  float ltx = fmaxf(a.x, b.x);
  float lty = fmaxf(a.y, b.y);
  float rbx = fminf(a.z, b.z);
  float rby = fminf(a.w, b.w);
  float wx = rbx - ltx; wx = wx > 0.0f ? wx : 0.0f;
  float wy = rby - lty; wy = wy > 0.0f ? wy : 0.0f;
  float inter = wx * wy;
  float un = areaA + areaB - inter;
  un = un > 1e-9f ? un : 1e-9f;
  return (inter / un) > 0.4f;
}

__device__ __forceinline__ u64 valid_word(int w, u32 vcnt) {
  int lo = w * 64;
  if ((int)vcnt >= lo + 64) return ~0ull;
  if ((int)vcnt <= lo) return 0ull;
  return (1ull << (vcnt - (u32)lo)) - 1ull;
}

// K0: zero meta (dispatch-boundary coherent). Keeps correctness independent of
// the poison value; the self-clean discipline in k_fused makes this belt+suspenders.
__global__ void __launch_bounds__(256) k_zero(u32* __restrict__ meta) {
  for (int k = threadIdx.x; k < META_U32; k += 256) meta[k] = 0;
}

__global__ void __launch_bounds__(256) k_fused(
    const float* __restrict__ s8, const float* __restrict__ s16, const float* __restrict__ s32,
    const float* __restrict__ bb8,  const float* __restrict__ kp8,
    const float* __restrict__ bb16, const float* __restrict__ kp16,
    const float* __restrict__ bb32, const float* __restrict__ kp32,
    u32* __restrict__ part, u32* red, u32* meta, u64* nzWords, u64* list, u64* mask,
    float* out) {
  __shared__ __align__(16) char smem[36864];
  __shared__ u32 sB, sCntE, sCntF, sBase;
  __shared__ u32 cnt16[16], sPc[16], sOff17[17];
  __shared__ u64 sRem[NWORDS];
  __shared__ int isLast;
  const int t = threadIdx.x, blk = blockIdx.x;
  const int wave = t >> 6, lane = t & 63;
  const int v = blk * 256 + t;
  u64* o64 = (u64*)out;

  // ---- phase A: per-block LDS histogram -> u16-packed partial (sc1) ----
  u32* lh = (u32*)smem;
#pragma unroll
  for (int k = 0; k < 16; ++k) lh[k * 256 + t] = 0;
  __syncthreads();
  float4 x = make_float4(-1.f, -1.f, -1.f, -1.f);
  if (v < NTOT4) {
    x = load_logit4(v, s8, s16, s32);
    if (x.x > 0.0f) atomicAdd(&lh[bucket_of(x.x)], 1u);
    if (x.y > 0.0f) atomicAdd(&lh[bucket_of(x.y)], 1u);
    if (x.z > 0.0f) atomicAdd(&lh[bucket_of(x.z)], 1u);
    if (x.w > 0.0f) atomicAdd(&lh[bucket_of(x.w)], 1u);
  }
  __syncthreads();
#pragma unroll
  for (int k = 0; k < 8; ++k) {           // per-block bin count <= 1024, fits u16
    int w = k * 256 + t;
    ast32(&part[blk * 2048 + w], lh[2 * w] | (lh[2 * w + 1] << 16));
  }
  __syncthreads();                         // drain sc1 partial stores
  if (t == 0 && arrive_last(&meta[MI_ARRA], NBLK))
    publish(&meta[MI_REDA], 0xC0DE0000u);

  // ---- phase B: 32 reducer blocks, 128 bins (64 packed words) each ----
  if (blk < NRED) {
    u32* llo = (u32*)smem;                 // [256]
    u32* lhi = llo + 256;                  // [256]
    if (t == 0) spin_tag<2>(&meta[MI_REDA]);
    __syncthreads();
    int w = t & 63, pp = t >> 6;           // 4-way slice over the 168 partials
    u32 lo = 0, hi = 0;
    for (int p = pp; p < NBLK; p += 4) {
      u32 pv = ald32(&part[p * 2048 + blk * 64 + w]);
      lo += pv & 0xFFFFu; hi += pv >> 16;
    }
    llo[t] = lo; lhi[t] = hi;
    __syncthreads();
    if (t < 64) {
      u32 l = llo[t] + llo[64 + t] + llo[128 + t] + llo[192 + t];
      u32 h = lhi[t] + lhi[64 + t] + lhi[128 + t] + lhi[192 + t];
      ast32(&red[blk * 128 + 2 * t], l);
      ast32(&red[blk * 128 + 2 * t + 1], h);
    }
    __syncthreads();                       // drain sc1 red stores
    if (t == 0 && arrive_last(&meta[MI_ARRB], NRED)) {
      ast32(&meta[MI_REDA], 0u);           // last consumer cleans the flag
      publish(&meta[MI_REDD], 0xC0DE0000u);
    }
  }

  // ---- phase C: block 0 finds B; zeroes nzWords before publishing ----
  if (blk == 0) {
    if (t == 0) { spin_tag<2>(&meta[MI_REDD]); ast32(&meta[MI_REDD], 0u); }
    __syncthreads();
    u32* hloc = (u32*)smem;
    u32* csum = (u32*)(smem + 16384);
#pragma unroll
    for (int k = 0; k < 16; ++k) hloc[k * 256 + t] = ald32(&red[k * 256 + t]);
    if (t < NWORDS) ast64(&nzWords[t], 0ull);     // drained at next barrier, pre-B
    __syncthreads();
    u32 sum = 0;
    int base = t * 16;
#pragma unroll
    for (int k = 0; k < 16; ++k) sum += hloc[base + k];
    csum[t] = sum;
    __syncthreads();
    for (int off = 1; off < 256; off <<= 1) {     // inclusive suffix scan
      u32 add = (t + off < 256) ? csum[t + off] : 0u;
      __syncthreads();
      csum[t] += add;
      __syncthreads();
    }
    u32 above = (t < 255) ? csum[t + 1] : 0u;
    if (t == 0 && csum[0] < TOPK) ast32(&meta[MI_B], 0xC0DE0000u);   // B=0
    if (csum[t] >= TOPK && above < TOPK) {        // exactly one thread
      u32 cum = above, Bv = (u32)(t * 16);
      for (int b = t * 16 + 15; b >= t * 16; --b) {
        cum += hloc[b];
        if (cum >= TOPK) { Bv = (u32)b; break; }
      }
      ast32(&meta[MI_B], 0xC0DE0000u | Bv);
    }
  }

  // ---- phase D: all 168 blocks: compact using the registers from phase A ----
  if (t == 0) sB = spin_tag<4>(&meta[MI_B]) & 0xFFFFu;
  __syncthreads();
  const u32 B = sB;
  u32 win = 0;
  float c[4] = {x.x, x.y, x.z, x.w};
  if (v < NTOT4) {
#pragma unroll
    for (int j = 0; j < 4; ++j)
      if (c[j] > 0.0f && bucket_of(c[j]) >= B) win |= 1u << j;
  }
  u32 wpos[4], wcnt[4];
#pragma unroll
  for (int j = 0; j < 4; ++j) {                   // wave-uniform ballots
    u64 bal = __ballot((win >> j) & 1u);
    wcnt[j] = (u32)__popcll(bal);
    wpos[j] = (u32)__popcll(bal & ((1ull << lane) - 1ull));
  }
  if (lane == 0) {
#pragma unroll
    for (int j = 0; j < 4; ++j) cnt16[wave * 4 + j] = wcnt[j];
  }
  __syncthreads();
  if (t == 0) {                                   // ONE list-count RMW per block
    u32 tot = 0, pre[16];
#pragma unroll
    for (int k = 0; k < 16; ++k) { pre[k] = tot; tot += cnt16[k]; }
#pragma unroll
    for (int k = 0; k < 16; ++k) cnt16[k] = pre[k];
    sBase = tot ? normc(__hip_atomic_fetch_add(&meta[MI_CNT], tot, __ATOMIC_RELAXED,
                                               __HIP_MEMORY_SCOPE_AGENT))
                : 0u;
  }
  __syncthreads();
#pragma unroll
  for (int j = 0; j < 4; ++j) {
    if ((win >> j) & 1u) {
      u32 dst = sBase + cnt16[wave * 4 + j] + wpos[j];
      if (dst < LIST_CAP) {
        u32 idx = (u32)(v * 4 + j);
        ast64(&list[dst], ((u64)__float_as_uint(c[j]) << 32) | (u64)(~idx));
      }
    }
  }
  __syncthreads();                                // drain sc1 list stores
  if (t == 0 && arrive_last(&meta[MI_CMP], NBLK)) {
    u32 cc = normc(ald32(&meta[MI_CNT]));         // all CNT RMWs complete
    if (cc > LIST_CAP) cc = LIST_CAP;
    ast32(&meta[MI_CNT], 0u);                     // cleanup for next launch
    ast32(&meta[MI_B], 0u);                       // all 168 passed the B spin
    publish(&meta[MI_CMPD], 0xC0DE0000u | cc);
  }
  if (blk >= IOU_BLKS) return;                    // blocks 63..167 are done

  // ---- phase E: blocks 0..31: exact rank (desc key) + decode; out via sc1 ----
  if (blk < RANK_BLKS) {
    if (t == 0) sCntE = spin_tag<4>(&meta[MI_CMPD]) & 0xFFFFu;
    __syncthreads();
    const u32 cnt = sCntE;
    u64* keys = (u64*)smem;
    for (int j = t; j < LIST_CAP; j += 256) keys[j] = (j < (int)cnt) ? ald64(&list[j]) : 0ull;
    __syncthreads();
    if (t < 64) {                 // 1 active wave/block: LDS pipe uncontended
      int tid = blk * 64 + t;     // candidate id, 0..2047
      if (tid < (int)cnt) {
        u64 my = keys[tid];
        int rank = 0, j = 0;
        for (; j + 4 <= (int)cnt; j += 4)
          rank += (keys[j] > my) + (keys[j + 1] > my) + (keys[j + 2] > my) + (keys[j + 3] > my);
        for (; j < (int)cnt; ++j) rank += (keys[j] > my);
        if (rank < TOPK) {
          float lx = __uint_as_float((u32)(my >> 32));
          float sc = (float)(1.0 / (1.0 + exp(-(double)lx)));   // sigmoid f64, round once
          u32 idx = ~((u32)my);
          float4 box;
          float kv[10];
          int p, xq, yq;
          float st;
          const float *bb, *kp;
          if (idx < N8) {
            st = 8.f;  p = (int)idx;              xq = p % 480; yq = p / 480; bb = bb8;  kp = kp8;
          } else if (idx < N8 + N16) {
            st = 16.f; p = (int)idx - N8;         xq = p % 240; yq = p / 240; bb = bb16; kp = kp16;
          } else {
            st = 32.f; p = (int)idx - (N8 + N16); xq = p % 120; yq = p / 120; bb = bb32; kp = kp32;
          }
          float cx = (float)xq * st, cy = (float)yq * st;
          {
#pragma clang fp contract(off)
            float d0 = bb[4 * p + 0] * st;
            float d1 = bb[4 * p + 1] * st;
            float d2 = bb[4 * p + 2] * st;
            float d3 = bb[4 * p + 3] * st;
            box.x = cx - d0; box.y = cy - d1; box.z = cx + d2; box.w = cy + d3;
            for (int q = 0; q < 10; ++q)
              kv[q] = kp[10 * p + q] * st + ((q & 1) ? cy : cx);
          }
          ast64(&o64[2 * rank],     ((u64)__float_as_uint(box.y) << 32) | __float_as_uint(box.x));
          ast64(&o64[2 * rank + 1], ((u64)__float_as_uint(box.w) << 32) | __float_as_uint(box.z));
          ast32(&((u32*)out)[4000 + rank], __float_as_uint(sc));
          int wb = 2500 + 5 * rank;
#pragma unroll
          for (int q = 0; q < 5; ++q)
            ast64(&o64[wb + q],
                  ((u64)__float_as_uint(kv[2 * q + 1]) << 32) | __float_as_uint(kv[2 * q]));
        }
      } else if (tid < TOPK) {    // unfilled rows: zero
        ast64(&o64[2 * tid], 0ull); ast64(&o64[2 * tid + 1], 0ull);
        ast32(&((u32*)out)[4000 + tid], 0u);
        int wb = 2500 + 5 * tid;
#pragma unroll
        for (int q = 0; q < 5; ++q) ast64(&o64[wb + q], 0ull);
      }
    }
    __syncthreads();              // drain sc1 out stores
    if (t == 0 && arrive_last(&meta[MI_DEC], RANK_BLKS)) {
      ast32(&meta[MI_CMPD], 0u);  // all 32 rank blocks passed the CMPD spin
      publish(&meta[MI_DECD], 0xC0DE0000u | cnt);
    }
  }

  // ---- phase F: blocks 0..62: suppression bitmask + last-arriver greedy NMS ----
  if (t == 0) sCntF = spin_tag<4>(&meta[MI_DECD]) & 0xFFFFu;
  __syncthreads();
  {
    float4* boxes = (float4*)smem;
    for (int r = t; r < TOPK; r += 256) {
      u64 a = ald64(&o64[2 * r]), b = ald64(&o64[2 * r + 1]);
      float4 bx;
      bx.x = __uint_as_float((u32)a); bx.y = __uint_as_float((u32)(a >> 32));
      bx.z = __uint_as_float((u32)b); bx.w = __uint_as_float((u32)(b >> 32));
      boxes[r] = bx;
    }
    __syncthreads();
    int task = blk * 256 + t;
    if (task < IOU_TASKS) {
      int w = task / 1000;          // 0..15  (wave-mostly-uniform)
      int i = task - w * 1000;      // 0..999 (consecutive per lane -> coalesced)
      float4 a = boxes[i];
      int bse = w * 64;
      int jend = (bse + 64) < TOPK ? (bse + 64) : TOPK;
      u64 bits = 0;
      for (int j = bse; j < jend; ++j)          // boxes[j] wave-broadcast
        if (j > i && iou_gt04(a, boxes[j])) bits |= 1ull << (j - bse);
      ast64(&mask[(u64)w * 1000 + i], bits);    // coalesced (transposed layout)
      if (bits) atomicOr(&nzWords[i >> 6], 1ull << (i & 63));
    }
    __syncthreads();                // drain sc1 mask stores + atomics
    if (t == 0) {
      bool lastF = arrive_last(&meta[MI_IOU], IOU_BLKS);
      if (lastF) ast32(&meta[MI_DECD], 0u);     // all 63 passed the DECD spin
      isLast = lastF ? 1 : 0;
    }
    __syncthreads();
    if (!isLast) return;

    // exact greedy NMS over nonzero-mask rows only (skipping empty rows is exact)
    const u32 vcnt = sCntF < TOPK ? sCntF : TOPK;
    u32* rows = (u32*)smem;               // up to 1000 row ids (4 KB)
    u64* cache = (u64*)(smem + 4096);     // NMS_CACHE x 16 u64 (32 KB)
    u64 nzv = 0;
    if (t < NWORDS) {
      nzv = ald64(&nzWords[t]) & valid_word(t, vcnt);
      sPc[t] = (u32)__popcll(nzv);
    }
    __syncthreads();
    if (t == 0) {
      u32 o = 0;
      for (int w = 0; w < NWORDS; ++w) { sOff17[w] = o; o += sPc[w]; }
      sOff17[16] = o;
    }
    __syncthreads();
    if (t < NWORDS) {                     // expand to ascending row list
      u64 m = nzv;
      u32 o = sOff17[t];
      while (m) { int b = __builtin_ctzll(m); m &= m - 1; rows[o++] = (u32)(t * 64 + b); }
    }
    __syncthreads();
    const int S = (int)sOff17[16];
    const int Sc = S < NMS_CACHE ? S : NMS_CACHE;
    for (int idx = t; idx < Sc * NWORDS; idx += 256) {   // parallel mask prefetch
      int s = idx >> 4, w = idx & 15;
      cache[s * NWORDS + w] = ald64(&mask[(u64)w * 1000 + rows[s]]);
    }
    __syncthreads();
    if (t < 64) {                 // serial greedy chain; lane<16 owns word `lane`
      u64 remv = 0;
      for (int s = 0; s < S; ++s) {
        u32 row = rows[s];
        int cc = (int)(row >> 6), b = (int)(row & 63);
        u64 remc = __shfl(remv, cc);
        if (!((remc >> b) & 1ull)) {     // row alive -> apply its suppression row
          u64 m = 0;
          if (t < NWORDS)
            m = (s < NMS_CACHE) ? cache[s * NWORDS + t] : ald64(&mask[(u64)t * 1000 + row]);
          remv |= m;
        }
      }
      if (t < NWORDS) sRem[t] = valid_word(t, vcnt) & remv;
    }
    __syncthreads();
    for (int r = t; r < TOPK; r += 256) {
      if ((sRem[r >> 6] >> (r & 63)) & 1ull) {
        ast64(&o64[2 * r], 0ull); ast64(&o64[2 * r + 1], 0ull);
        ast32(&((u32*)out)[4000 + r], 0u);
        int wb = 2500 + 5 * r;
#pragma unroll
        for (int q = 0; q < 5; ++q) ast64(&o64[wb + q], 0ull);
      }
    }
  }
}

extern "C" void kernel_launch(void* const* d_in, const int* in_sizes, int n_in,
                              void* d_out, int out_size, void* d_ws, size_t ws_size,
                              hipStream_t stream) {
  const float* s8   = (const float*)d_in[1];
  const float* bb8  = (const float*)d_in[2];
  const float* kp8  = (const float*)d_in[3];
  const float* s16  = (const float*)d_in[4];
  const float* bb16 = (const float*)d_in[5];
  const float* kp16 = (const float*)d_in[6];
  const float* s32  = (const float*)d_in[7];
  const float* bb32 = (const float*)d_in[8];
  const float* kp32 = (const float*)d_in[9];

  char* ws = (char*)d_ws;
  u32* part    = (u32*)(ws + OFF_PART);
  u32* red     = (u32*)(ws + OFF_RED);
  u32* meta    = (u32*)(ws + OFF_META);
  u64* nzWords = (u64*)(ws + OFF_NZ);
  u64* list    = (u64*)(ws + OFF_LIST);
  u64* mask    = (u64*)(ws + OFF_MASK);
  float* out   = (float*)d_out;

  k_zero<<<1, 256, 0, stream>>>(meta);
  k_fused<<<NBLK, 256, 0, stream>>>(s8, s16, s32, bb8, kp8, bb16, kp16, bb32, kp32,
                                    part, red, meta, nzWords, list, mask, out);
}

// Round 4
// 197.271 us; speedup vs baseline: 1.0076x; 1.0076x over previous
//
#include <hip/hip_runtime.h>
#include <stdint.h>

typedef unsigned int u32;
typedef unsigned long long u64;

#define N8   130560   // (2176/8)*(3840/8)   = 272*480
#define N16  32640    // (2176/16)*(3840/16) = 136*240
#define N32  8160     // (2176/32)*(3840/32) = 68*120
#define NTOT 171360
#define NTOT4 42840   // NTOT/4
#define TOPK 1000
#define NWORDS 16
#define NBINS 4096
#define BUCKET_SCALE 682.0f
#define NBLK 63            // one block per CU slice; ALL phases use the same 63 blocks
#define NTHR 256
#define STRIDE (NBLK*NTHR) // 16128; each thread owns 3 strided float4s
#define LIST_CAP 2016      // 63*32: candidate cap (>= TOPK + bucket overshoot)
#define CPB 32             // candidates ranked per block (63*32 = 2016)
#define IOU_TASKS (TOPK * NWORDS)   // 16000
#define NMS_CACHE 256
#define POISON 0xAAAAAAAAu
#define SPIN_CAP (1u << 20)   // ~0.5s valve: deadlock -> wrong-but-completed run

// R12: attack the sync fabric (R11 counters: 60.9us kernel, VALUBusy 1.3% -> ~all
// waiting at the IF point). Changes: (1) 63 blocks (arrive widths & poller counts
// /2.7); (2) global-atomic histogram + findB by the last arriver (kills 2 handoffs,
// the 2.6MB partial traffic, and the reducer stage); (3) 8-way replicated flag
// lines (<=8 pollers each); (4) k_zero dropped -> SINGLE dispatch (poison-
// normalized counters make it safe); (5) rank split 8 threads/candidate.
// All handoffs remain the validated sc1 + syncthreads-vmcnt-drain + arrive-RMW +
// 0xC0DE-tag pattern. Flag lifecycle: each flag reset by the publisher of the
// NEXT stage (provably after all its pollers passed); counters self-reset.

// meta u32 indices — ONE sync variable per 512 B line
#define MI_ARRA 0                  // phase A arrive ctr
#define MI_B(c)    (128*(1+(c)))   // 8 B-flag copies, lines 1..8
#define MI_CNT     (128*9)         // list count RMW line
#define MI_CMP     (128*10)        // compact arrive ctr
#define MI_CMPD(c) (128*(11+(c)))  // 8 copies, lines 11..18
#define MI_DEC     (128*19)        // decode arrive ctr
#define MI_DECD(c) (128*(20+(c)))  // 8 copies, lines 20..27
#define MI_IOU     (128*28)        // iou arrive ctr
#define META_U32   (128*29)

// workspace layout (bytes)
#define OFF_HIST 0         // u32[4096] global histogram (poison-tolerant, self-cleaned)
#define OFF_META 16384     // u32[META_U32]
#define OFF_NZ   32768     // u64[16]
#define OFF_LIST 33024     // u64[2016]
#define OFF_MASK 49152     // u64[16*1000] transposed: mask[w*1000+i]

__device__ __forceinline__ u32 ald32(const u32* p) {
  return __hip_atomic_load(p, __ATOMIC_RELAXED, __HIP_MEMORY_SCOPE_AGENT);
}
__device__ __forceinline__ u64 ald64(const u64* p) {
  return __hip_atomic_load(p, __ATOMIC_RELAXED, __HIP_MEMORY_SCOPE_AGENT);
}
__device__ __forceinline__ void ast32(u32* p, u32 v) {
  __hip_atomic_store(p, v, __ATOMIC_RELAXED, __HIP_MEMORY_SCOPE_AGENT);
}
__device__ __forceinline__ void ast64(u64* p, u64 v) {
  __hip_atomic_store(p, v, __ATOMIC_RELAXED, __HIP_MEMORY_SCOPE_AGENT);
}
__device__ __forceinline__ void publish(u32* p, u32 v) {
  __hip_atomic_store(p, v, __ATOMIC_RELEASE, __HIP_MEMORY_SCOPE_AGENT);
}
template <int SLP>
__device__ __forceinline__ u32 spin_tag(const u32* p) {
  u32 v, it = 0;
  while (((v = ald32(p)) >> 16) != 0xC0DEu) {
    __builtin_amdgcn_s_sleep(SLP);
    if (++it > SPIN_CAP) break;
  }
  return v;
}
__device__ __forceinline__ u32 normc(u32 v) {   // tolerate 0xAAAAAAAA poison base
  return v >= 0x80000000u ? v - POISON : v;
}
__device__ __forceinline__ bool arrive_last(u32* p, u32 total) {
  u32 old = __hip_atomic_fetch_add(p, 1u, __ATOMIC_RELAXED, __HIP_MEMORY_SCOPE_AGENT);
  if (normc(old) == total - 1u) { ast32(p, 0u); return true; }
  return false;
}

__device__ __forceinline__ u32 bucket_of(float x) {
  u32 b = (u32)(x * BUCKET_SCALE);
  return b > (NBINS - 1) ? (NBINS - 1) : b;
}

__device__ __forceinline__ float4 load_logit4(int v, const float* s8, const float* s16,
                                              const float* s32) {
  int e = v * 4;
  if (e < N8) return ((const float4*)s8)[v];
  if (e < N8 + N16) return ((const float4*)s16)[v - N8 / 4];
  return ((const float4*)s32)[v - (N8 + N16) / 4];
}

__device__ __forceinline__ bool iou_gt04(float4 a, float4 b) {
#pragma clang fp contract(off)
  float areaA = (a.z - a.x) * (a.w - a.y);
  float areaB = (b.z - b.x) * (b.w - b.y);
  float ltx = fmaxf(a.x, b.x);
  float lty = fmaxf(a.y, b.y);
  float rbx = fminf(a.z, b.z);
  float rby = fminf(a.w, b.w);
  float wx = rbx - ltx; wx = wx > 0.0f ? wx : 0.0f;
  float wy = rby - lty; wy = wy > 0.0f ? wy : 0.0f;
  float inter = wx * wy;
  float un = areaA + areaB - inter;
  un = un > 1e-9f ? un : 1e-9f;
  return (inter / un) > 0.4f;
}

__device__ __forceinline__ u64 valid_word(int w, u32 vcnt) {
  int lo = w * 64;
  if ((int)vcnt >= lo + 64) return ~0ull;
  if ((int)vcnt <= lo) return 0ull;
  return (1ull << (vcnt - (u32)lo)) - 1ull;
}

__global__ void __launch_bounds__(256) k_all(
    const float* __restrict__ s8, const float* __restrict__ s16, const float* __restrict__ s32,
    const float* __restrict__ bb8,  const float* __restrict__ kp8,
    const float* __restrict__ bb16, const float* __restrict__ kp16,
    const float* __restrict__ bb32, const float* __restrict__ kp32,
    u32* hist, u32* meta, u64* nzWords, u64* list, u64* mask, float* out) {
  __shared__ __align__(16) char smem[36864];
  __shared__ u32 sB, sBpub, sCntE, sCntF, sBase;
  __shared__ int sFind, isLast;
  __shared__ u32 cnt48[48];
  __shared__ u32 sPc[16], sOff17[17];
  __shared__ u64 sRem[NWORDS];
  const int t = threadIdx.x, blk = blockIdx.x;
  const int wave = t >> 6, lane = t & 63;
  u64* o64 = (u64*)out;

  // ---- phase A: strided loads (3 float4/thread) + direct global hist atomics ----
  const int v0 = blk * NTHR + t;                 // < 16128, always valid
  float4 x0 = load_logit4(v0, s8, s16, s32);
  float4 x1 = load_logit4(v0 + STRIDE, s8, s16, s32);   // < 32256, always valid
  float4 x2 = make_float4(-1.f, -1.f, -1.f, -1.f);
  if (v0 + 2 * STRIDE < NTOT4) x2 = load_logit4(v0 + 2 * STRIDE, s8, s16, s32);
  float cv[12] = {x0.x, x0.y, x0.z, x0.w, x1.x, x1.y, x1.z, x1.w,
                  x2.x, x2.y, x2.z, x2.w};
#pragma unroll
  for (int j = 0; j < 12; ++j)
    if (cv[j] > 0.0f) atomicAdd(&hist[bucket_of(cv[j])], 1u);   // device-scope
  __syncthreads();                               // drain loads + atomics (vmcnt)
  if (t == 0) sFind = arrive_last(&meta[MI_ARRA], NBLK) ? 1 : 0;
  __syncthreads();

  // ---- phase B: the LAST arriver's block computes B and publishes 8 copies ----
  if (sFind) {
    u32* hloc = (u32*)smem;
    u32* csum = (u32*)(smem + 16384);
#pragma unroll
    for (int k = 0; k < 16; ++k) hloc[k * 256 + t] = normc(ald32(&hist[k * 256 + t]));
    if (t < NWORDS) ast64(&nzWords[t], 0ull);    // drained by the barriers below
    __syncthreads();
    u32 sum = 0;
    int base = t * 16;
#pragma unroll
    for (int k = 0; k < 16; ++k) sum += hloc[base + k];
    csum[t] = sum;
    __syncthreads();
    for (int off = 1; off < 256; off <<= 1) {    // inclusive suffix scan
      u32 add = (t + off < 256) ? csum[t + off] : 0u;
      __syncthreads();
      csum[t] += add;
      __syncthreads();
    }
    u32 above = (t < 255) ? csum[t + 1] : 0u;
    if (t == 0 && csum[0] < TOPK) sBpub = 0u;    // fewer than TOPK positives
    if (csum[t] >= TOPK && above < TOPK) {       // exactly one thread
      u32 cum = above, Bv = (u32)(t * 16);
      for (int b = t * 16 + 15; b >= t * 16; --b) {
        cum += hloc[b];
        if (cum >= TOPK) { Bv = (u32)b; break; }
      }
      sBpub = Bv;
    }
    __syncthreads();                             // sBpub ready; nz zeros drained
    if (t < 8) publish(&meta[MI_B(t)], 0xC0DE0000u | sBpub);
#pragma unroll
    for (int k = 0; k < 16; ++k) hist[k * 256 + t] = 0u;   // self-clean (off path)
  }

  // ---- phase D: all blocks poll their B copy (<=8 pollers/line), compact ----
  if (t == 0) sB = spin_tag<8>(&meta[MI_B(blk & 7)]) & 0xFFFFu;
  __syncthreads();
  const u32 B = sB;
  u32 winm = 0;
#pragma unroll
  for (int j = 0; j < 12; ++j)
    if (cv[j] > 0.0f && bucket_of(cv[j]) >= B) winm |= 1u << j;
  u32 wpos[12];
#pragma unroll
  for (int j = 0; j < 12; ++j) {                 // wave-uniform ballots
    u64 bal = __ballot((winm >> j) & 1u);
    if (lane == 0) cnt48[wave * 12 + j] = (u32)__popcll(bal);
    wpos[j] = (u32)__popcll(bal & ((1ull << lane) - 1ull));
  }
  __syncthreads();
  if (t == 0) {                                  // ONE list-count RMW per block
    u32 tot = 0, pre;
#pragma unroll
    for (int k = 0; k < 48; ++k) { pre = tot; tot += cnt48[k]; cnt48[k] = pre; }
    sBase = tot ? normc(__hip_atomic_fetch_add(&meta[MI_CNT], tot, __ATOMIC_RELAXED,
                                               __HIP_MEMORY_SCOPE_AGENT))
                : 0u;
  }
  __syncthreads();
#pragma unroll
  for (int j = 0; j < 12; ++j) {
    if ((winm >> j) & 1u) {
      u32 dst = sBase + cnt48[wave * 12 + j] + wpos[j];
      if (dst < LIST_CAP) {
        u32 idx = (u32)((v0 + (j >> 2) * STRIDE) * 4 + (j & 3));
        ast64(&list[dst], ((u64)__float_as_uint(cv[j]) << 32) | (u64)(~idx));
      }
    }
  }
  __syncthreads();                               // drain sc1 list stores
  if (t == 0 && arrive_last(&meta[MI_CMP], NBLK)) {
    u32 cc = normc(ald32(&meta[MI_CNT]));        // all CNT RMWs complete
    if (cc > LIST_CAP) cc = LIST_CAP;
    ast32(&meta[MI_CNT], 0u);
#pragma unroll
    for (int c = 0; c < 8; ++c) ast32(&meta[MI_B(c)], 0u);   // all passed B spin
#pragma unroll
    for (int c = 0; c < 8; ++c) publish(&meta[MI_CMPD(c)], 0xC0DE0000u | cc);
  }

  // ---- phase E: rank (8 key-slices/candidate) + decode; out via sc1 ----
  if (t == 0) sCntE = spin_tag<8>(&meta[MI_CMPD(blk & 7)]) & 0xFFFFu;
  __syncthreads();
  const u32 cnt = sCntE;
  {
    u64* keys = (u64*)smem;                      // 2016*8 = 16128 B
    u32* rpart = (u32*)(smem + 16384);           // 256*4 = 1 KB
    for (int j = t; j < LIST_CAP; j += NTHR)
      keys[j] = (j < (int)cnt) ? ald64(&list[j]) : 0ull;
    __syncthreads();
    {
      const int ci = t & 31, sl = t >> 5;        // candidate-in-block, key-slice
      const int c = blk * CPB + ci;              // 0..2015
      const int chunk = ((int)cnt + 7) >> 3;
      int lo = sl * chunk; if (lo > (int)cnt) lo = (int)cnt;
      int hi = lo + chunk; if (hi > (int)cnt) hi = (int)cnt;
      u64 my = keys[c];
      int r = 0, j = lo;
      for (; j + 4 <= hi; j += 4)
        r += (keys[j] > my) + (keys[j + 1] > my) + (keys[j + 2] > my) + (keys[j + 3] > my);
      for (; j < hi; ++j) r += (keys[j] > my);
      rpart[t] = (u32)r;
    }
    __syncthreads();
    if (t < CPB) {
      const int c = blk * CPB + t;
      if (c < (int)cnt) {
        int rank = 0;
#pragma unroll
        for (int q = 0; q < 8; ++q) rank += (int)rpart[t + 32 * q];
        if (rank < TOPK) {
          u64 my = keys[c];
          float lx = __uint_as_float((u32)(my >> 32));
          float sc = (float)(1.0 / (1.0 + exp(-(double)lx)));   // f64 sigmoid, round once
          u32 idx = ~((u32)my);
          float4 box;
          float kv[10];
          int p, xq, yq;
          float st;
          const float *bb, *kp;
          if (idx < N8) {
            st = 8.f;  p = (int)idx;              xq = p % 480; yq = p / 480; bb = bb8;  kp = kp8;
          } else if (idx < N8 + N16) {
            st = 16.f; p = (int)idx - N8;         xq = p % 240; yq = p / 240; bb = bb16; kp = kp16;
          } else {
            st = 32.f; p = (int)idx - (N8 + N16); xq = p % 120; yq = p / 120; bb = bb32; kp = kp32;
          }
          float cx = (float)xq * st, cy = (float)yq * st;
          {
#pragma clang fp contract(off)
            float d0 = bb[4 * p + 0] * st;
            float d1 = bb[4 * p + 1] * st;
            float d2 = bb[4 * p + 2] * st;
            float d3 = bb[4 * p + 3] * st;
            box.x = cx - d0; box.y = cy - d1; box.z = cx + d2; box.w = cy + d3;
            for (int q = 0; q < 10; ++q)
              kv[q] = kp[10 * p + q] * st + ((q & 1) ? cy : cx);
          }
          ast64(&o64[2 * rank],     ((u64)__float_as_uint(box.y) << 32) | __float_as_uint(box.x));
          ast64(&o64[2 * rank + 1], ((u64)__float_as_uint(box.w) << 32) | __float_as_uint(box.z));
          ast32(&((u32*)out)[4000 + rank], __float_as_uint(sc));
          int wb = 2500 + 5 * rank;
#pragma unroll
          for (int q = 0; q < 5; ++q)
            ast64(&o64[wb + q],
                  ((u64)__float_as_uint(kv[2 * q + 1]) << 32) | __float_as_uint(kv[2 * q]));
        }
      } else if (c < TOPK) {       // unfilled rows: zero
        ast64(&o64[2 * c], 0ull); ast64(&o64[2 * c + 1], 0ull);
        ast32(&((u32*)out)[4000 + c], 0u);
        int wb = 2500 + 5 * c;
#pragma unroll
        for (int q = 0; q < 5; ++q) ast64(&o64[wb + q], 0ull);
      }
    }
  }
  __syncthreads();                               // drain sc1 out stores
  if (t == 0 && arrive_last(&meta[MI_DEC], NBLK)) {
#pragma unroll
    for (int c = 0; c < 8; ++c) ast32(&meta[MI_CMPD(c)], 0u);  // all passed CMPD spin
#pragma unroll
    for (int c = 0; c < 8; ++c) publish(&meta[MI_DECD(c)], 0xC0DE0000u | cnt);
  }

  // ---- phase F: IOU bitmask (63 blocks) + last-arriver greedy NMS ----
  if (t == 0) sCntF = spin_tag<8>(&meta[MI_DECD(blk & 7)]) & 0xFFFFu;
  __syncthreads();
  {
    float4* boxes = (float4*)smem;
    for (int r = t; r < TOPK; r += NTHR) {
      u64 a = ald64(&o64[2 * r]), b = ald64(&o64[2 * r + 1]);
      float4 bx;
      bx.x = __uint_as_float((u32)a); bx.y = __uint_as_float((u32)(a >> 32));
      bx.z = __uint_as_float((u32)b); bx.w = __uint_as_float((u32)(b >> 32));
      boxes[r] = bx;
    }
    __syncthreads();
    int task = blk * NTHR + t;
    if (task < IOU_TASKS) {
      int w = task / 1000;          // 0..15  (wave-mostly-uniform)
      int i = task - w * 1000;      // 0..999 (consecutive per lane -> coalesced)
      float4 a = boxes[i];
      int bse = w * 64;
      int jend = (bse + 64) < TOPK ? (bse + 64) : TOPK;
      u64 bits = 0;
      for (int j = bse; j < jend; ++j)          // boxes[j] wave-broadcast
        if (j > i && iou_gt04(a, boxes[j])) bits |= 1ull << (j - bse);
      ast64(&mask[(u64)w * 1000 + i], bits);    // coalesced (transposed layout)
      if (bits) atomicOr(&nzWords[i >> 6], 1ull << (i & 63));
    }
    __syncthreads();                // drain sc1 mask stores + atomics
    if (t == 0) {
      int last = arrive_last(&meta[MI_IOU], NBLK) ? 1 : 0;
      if (last) {
#pragma unroll
        for (int c = 0; c < 8; ++c) ast32(&meta[MI_DECD(c)], 0u);  // all passed
      }
      isLast = last;
    }
    __syncthreads();
    if (!isLast) return;

    // exact greedy NMS over nonzero-mask rows only (skipping empty rows is exact)
    const u32 vcnt = sCntF < TOPK ? sCntF : TOPK;
    u32* rows = (u32*)smem;               // up to 1000 row ids (4 KB)
    u64* cache = (u64*)(smem + 4096);     // NMS_CACHE x 16 u64 (32 KB)
    u64 nzv = 0;
    if (t < NWORDS) {
      nzv = ald64(&nzWords[t]) & valid_word(t, vcnt);
      sPc[t] = (u32)__popcll(nzv);
    }
    __syncthreads();
    if (t == 0) {
      u32 o = 0;
      for (int w = 0; w < NWORDS; ++w) { sOff17[w] = o; o += sPc[w]; }
      sOff17[16] = o;
    }
    __syncthreads();
    if (t < NWORDS) {                     // expand to ascending row list
      u64 m = nzv;
      u32 o = sOff17[t];
      while (m) { int b = __builtin_ctzll(m); m &= m - 1; rows[o++] = (u32)(t * 64 + b); }
    }
    __syncthreads();
    const int S = (int)sOff17[16];
    const int Sc = S < NMS_CACHE ? S : NMS_CACHE;
    for (int idx = t; idx < Sc * NWORDS; idx += NTHR) {   // parallel mask prefetch
      int s = idx >> 4, w = idx & 15;
      cache[s * NWORDS + w] = ald64(&mask[(u64)w * 1000 + rows[s]]);
    }
    __syncthreads();
    if (t < 64) {                 // serial greedy chain; lane<16 owns word `lane`
      u64 remv = 0;
      for (int s = 0; s < S; ++s) {
        u32 row = rows[s];
        int cc = (int)(row >> 6), b = (int)(row & 63);
        u64 remc = __shfl(remv, cc);
        if (!((remc >> b) & 1ull)) {     // row alive -> apply its suppression row
          u64 m = 0;
          if (t < NWORDS)
            m = (s < NMS_CACHE) ? cache[s * NWORDS + t] : ald64(&mask[(u64)t * 1000 + row]);
          remv |= m;
        }
      }
      if (t < NWORDS) sRem[t] = valid_word(t, vcnt) & remv;
    }
    __syncthreads();
    for (int r = t; r < TOPK; r += NTHR) {
      if ((sRem[r >> 6] >> (r & 63)) & 1ull) {
        ast64(&o64[2 * r], 0ull); ast64(&o64[2 * r + 1], 0ull);
        ast32(&((u32*)out)[4000 + r], 0u);
        int wb = 2500 + 5 * r;
#pragma unroll
        for (int q = 0; q < 5; ++q) ast64(&o64[wb + q], 0ull);
      }
    }
  }
}

extern "C" void kernel_launch(void* const* d_in, const int* in_sizes, int n_in,
                              void* d_out, int out_size, void* d_ws, size_t ws_size,
                              hipStream_t stream) {
  const float* s8   = (const float*)d_in[1];
  const float* bb8  = (const float*)d_in[2];
  const float* kp8  = (const float*)d_in[3];
  const float* s16  = (const float*)d_in[4];
  const float* bb16 = (const float*)d_in[5];
  const float* kp16 = (const float*)d_in[6];
  const float* s32  = (const float*)d_in[7];
  const float* bb32 = (const float*)d_in[8];
  const float* kp32 = (const float*)d_in[9];

  char* ws = (char*)d_ws;
  u32* hist    = (u32*)(ws + OFF_HIST);
  u32* meta    = (u32*)(ws + OFF_META);
  u64* nzWords = (u64*)(ws + OFF_NZ);
  u64* list    = (u64*)(ws + OFF_LIST);
  u64* mask    = (u64*)(ws + OFF_MASK);
  float* out   = (float*)d_out;

  k_all<<<NBLK, NTHR, 0, stream>>>(s8, s16, s32, bb8, kp8, bb16, kp16, bb32, kp32,
                                   hist, meta, nzWords, list, mask, out);
}

// Round 5
// 177.951 us; speedup vs baseline: 1.1170x; 1.1086x over previous
//
#include <hip/hip_runtime.h>
#include <stdint.h>

typedef unsigned int u32;
typedef unsigned long long u64;

#define N8   130560   // (2176/8)*(3840/8)   = 272*480
#define N16  32640    // (2176/16)*(3840/16) = 136*240
#define N32  8160     // (2176/32)*(3840/32) = 68*120
#define NTOT 171360
#define NTOT4 42840   // NTOT/4
#define TOPK 1000
#define NWORDS 16
#define NBINS 4096
#define BUCKET_SCALE 682.0f
#define LIST_CAP 2016      // 63*32
#define CPB 32             // candidates ranked per block
#define HIST_BLKS 168      // ceil(NTOT4/256)
#define RED_BLKS 32
#define RANK_BLKS 63
#define IOU_BLKS 63
#define IOU_TASKS (TOPK * NWORDS)   // 16000
#define NMS_CACHE 256

// R13: 7-dispatch split, ZERO spin fabric. Post-mortems: R12's global-atomic hist
// cost ~13us (IF-serialized hot-bin RMWs; WRITE_SIZE +1.1MB signature) -> LDS hist
// restored. Fused designs pay ~700cy sc1 latency on EVERY data op and give no
// per-phase visibility; R0 evidence says dispatch boundaries are cheap. So each
// phase is its own dispatch with its optimal grid, all memory ops are plain cached
// L2 ops (dispatch-boundary coherent), and rocprof now reports per-phase timing —
// this round doubles as the per-phase profile we've never had.

#define MI_B   0
#define MI_CNT 1
#define META_U32 256

// workspace layout (bytes)
#define OFF_PART 0                  // u32[168*2048] u16-pair packed partial hist
#define OFF_RED  1376256            // u32[4096]
#define OFF_META 1392640            // u32[256]
#define OFF_NZ   1393664            // u64[16]
#define OFF_LIST 1393792            // u64[2016]
#define OFF_MASK 1409920            // u64[16*1000] transposed: mask[w*1000+i]

__device__ __forceinline__ u32 bucket_of(float x) {
  u32 b = (u32)(x * BUCKET_SCALE);
  return b > (NBINS - 1) ? (NBINS - 1) : b;
}

__device__ __forceinline__ float4 load_logit4(int v, const float* s8, const float* s16,
                                              const float* s32) {
  int e = v * 4;
  if (e < N8) return ((const float4*)s8)[v];
  if (e < N8 + N16) return ((const float4*)s16)[v - N8 / 4];
  return ((const float4*)s32)[v - (N8 + N16) / 4];
}

__device__ __forceinline__ bool iou_gt04(float4 a, float4 b) {
#pragma clang fp contract(off)
  float areaA = (a.z - a.x) * (a.w - a.y);
  float areaB = (b.z - b.x) * (b.w - b.y);
  float ltx = fmaxf(a.x, b.x);
  float lty = fmaxf(a.y, b.y);
  float rbx = fminf(a.z, b.z);
  float rby = fminf(a.w, b.w);
  float wx = rbx - ltx; wx = wx > 0.0f ? wx : 0.0f;
  float wy = rby - lty; wy = wy > 0.0f ? wy : 0.0f;
  float inter = wx * wy;
  float un = areaA + areaB - inter;
  un = un > 1e-9f ? un : 1e-9f;
  return (inter / un) > 0.4f;
}

__device__ __forceinline__ u64 valid_word(int w, u32 vcnt) {
  int lo = w * 64;
  if ((int)vcnt >= lo + 64) return ~0ull;
  if ((int)vcnt <= lo) return 0ull;
  return (1ull << (vcnt - (u32)lo)) - 1ull;
}

// K1: LDS histogram -> u16-packed partials (plain stores). blk0 zeroes meta+nz.
__global__ void __launch_bounds__(256) k1_hist(
    const float* __restrict__ s8, const float* __restrict__ s16, const float* __restrict__ s32,
    u32* __restrict__ part, u32* __restrict__ meta, u64* __restrict__ nz) {
  __shared__ u32 lh[NBINS];
  const int t = threadIdx.x, blk = blockIdx.x;
#pragma unroll
  for (int k = 0; k < 16; ++k) lh[k * 256 + t] = 0;
  __syncthreads();
  int v = blk * 256 + t;
  if (v < NTOT4) {
    float4 x = load_logit4(v, s8, s16, s32);
    if (x.x > 0.0f) atomicAdd(&lh[bucket_of(x.x)], 1u);
    if (x.y > 0.0f) atomicAdd(&lh[bucket_of(x.y)], 1u);
    if (x.z > 0.0f) atomicAdd(&lh[bucket_of(x.z)], 1u);
    if (x.w > 0.0f) atomicAdd(&lh[bucket_of(x.w)], 1u);
  }
  __syncthreads();
#pragma unroll
  for (int k = 0; k < 8; ++k) {             // per-block bin count <= 1024 -> u16 ok
    int w = k * 256 + t;
    part[blk * 2048 + w] = lh[2 * w] | (lh[2 * w + 1] << 16);
  }
  if (blk == 0) {
    if (t < META_U32) meta[t] = 0;
    if (t < NWORDS) nz[t] = 0ull;
  }
}

// K2: 32 blocks x 128 bins: reduce the 168 packed partials -> red[4096].
__global__ void __launch_bounds__(256) k2_reduce(
    const u32* __restrict__ part, u32* __restrict__ red) {
  __shared__ u32 llo[256], lhi[256];
  const int t = threadIdx.x, blk = blockIdx.x;
  const int w = t & 63, pp = t >> 6;        // word-in-slice, partial-stream
  u32 lo = 0, hi = 0;
  for (int p = pp; p < HIST_BLKS; p += 4) {
    u32 pv = part[p * 2048 + blk * 64 + w];
    lo += pv & 0xFFFFu; hi += pv >> 16;
  }
  llo[t] = lo; lhi[t] = hi;
  __syncthreads();
  if (t < 64) {
    u32 l = llo[t] + llo[64 + t] + llo[128 + t] + llo[192 + t];
    u32 h = lhi[t] + lhi[64 + t] + lhi[128 + t] + lhi[192 + t];
    red[blk * 128 + 2 * t] = l;
    red[blk * 128 + 2 * t + 1] = h;
  }
}

// K3: one block: suffix-scan red -> bucket threshold B -> meta[MI_B].
__global__ void __launch_bounds__(256) k3_findb(
    const u32* __restrict__ red, u32* __restrict__ meta) {
  __shared__ u32 hloc[NBINS];
  __shared__ u32 csum[256];
  const int t = threadIdx.x;
#pragma unroll
  for (int k = 0; k < 16; ++k) hloc[k * 256 + t] = red[k * 256 + t];
  __syncthreads();
  u32 sum = 0;
  int base = t * 16;
#pragma unroll
  for (int k = 0; k < 16; ++k) sum += hloc[base + k];
  csum[t] = sum;
  __syncthreads();
  for (int off = 1; off < 256; off <<= 1) {   // inclusive suffix scan
    u32 add = (t + off < 256) ? csum[t + off] : 0u;
    __syncthreads();
    csum[t] += add;
    __syncthreads();
  }
  u32 above = (t < 255) ? csum[t + 1] : 0u;
  if (t == 0 && csum[0] < TOPK) meta[MI_B] = 0u;   // fewer than TOPK positives
  if (csum[t] >= TOPK && above < TOPK) {           // exactly one thread
    u32 cum = above, Bv = (u32)(t * 16);
    for (int b = t * 16 + 15; b >= t * 16; --b) {
      cum += hloc[b];
      if (cum >= TOPK) { Bv = (u32)b; break; }
    }
    meta[MI_B] = Bv;
  }
}

// K4: block-aggregated compaction of bucket>=B candidates into list (plain stores).
__global__ void __launch_bounds__(256) k4_compact(
    const float* __restrict__ s8, const float* __restrict__ s16, const float* __restrict__ s32,
    u32* __restrict__ meta, u64* __restrict__ list) {
  __shared__ u32 sB, sBase;
  __shared__ u32 cnt16[16];
  const int t = threadIdx.x, blk = blockIdx.x;
  const int wave = t >> 6, lane = t & 63;
  const int v = blk * 256 + t;
  if (t == 0) sB = meta[MI_B];
  float4 x = make_float4(-1.f, -1.f, -1.f, -1.f);
  if (v < NTOT4) x = load_logit4(v, s8, s16, s32);
  __syncthreads();
  const u32 B = sB;
  float c[4] = {x.x, x.y, x.z, x.w};
  u32 win = 0;
#pragma unroll
  for (int j = 0; j < 4; ++j)
    if (c[j] > 0.0f && bucket_of(c[j]) >= B) win |= 1u << j;
  u32 wpos[4], wcnt[4];
#pragma unroll
  for (int j = 0; j < 4; ++j) {
    u64 bal = __ballot((win >> j) & 1u);
    wcnt[j] = (u32)__popcll(bal);
    wpos[j] = (u32)__popcll(bal & ((1ull << lane) - 1ull));
  }
  if (lane == 0) {
#pragma unroll
    for (int j = 0; j < 4; ++j) cnt16[wave * 4 + j] = wcnt[j];
  }
  __syncthreads();
  if (t == 0) {                       // ONE device-atomic RMW per block
    u32 tot = 0, pre[16];
#pragma unroll
    for (int k = 0; k < 16; ++k) { pre[k] = tot; tot += cnt16[k]; }
#pragma unroll
    for (int k = 0; k < 16; ++k) cnt16[k] = pre[k];
    sBase = tot ? atomicAdd(&meta[MI_CNT], tot) : 0u;
  }
  __syncthreads();
#pragma unroll
  for (int j = 0; j < 4; ++j) {
    if ((win >> j) & 1u) {
      u32 dst = sBase + cnt16[wave * 4 + j] + wpos[j];
      if (dst < LIST_CAP) {
        u32 idx = (u32)(v * 4 + j);
        list[dst] = ((u64)__float_as_uint(c[j]) << 32) | (u64)(~idx);
      }
    }
  }
}

// K5: 63 blocks: exact rank (8 key-slices per candidate) + decode -> out.
__global__ void __launch_bounds__(256) k5_rank(
    const u32* __restrict__ meta, const u64* __restrict__ list,
    const float* __restrict__ bb8,  const float* __restrict__ kp8,
    const float* __restrict__ bb16, const float* __restrict__ kp16,
    const float* __restrict__ bb32, const float* __restrict__ kp32,
    float* __restrict__ out) {
  __shared__ __align__(16) u64 keys[LIST_CAP];
  __shared__ u32 rpart[256];
  __shared__ u32 sCnt;
  const int t = threadIdx.x, blk = blockIdx.x;
  if (t == 0) { u32 cc = meta[MI_CNT]; sCnt = cc > LIST_CAP ? LIST_CAP : cc; }
  __syncthreads();
  const u32 cnt = sCnt;
  for (int j = t; j < LIST_CAP; j += 256) keys[j] = (j < (int)cnt) ? list[j] : 0ull;
  __syncthreads();
  {
    const int ci = t & 31, sl = t >> 5;       // candidate-in-block, key-slice
    const int c = blk * CPB + ci;
    const int chunk = ((int)cnt + 7) >> 3;
    int lo = sl * chunk; if (lo > (int)cnt) lo = (int)cnt;
    int hi = lo + chunk; if (hi > (int)cnt) hi = (int)cnt;
    u64 my = keys[c];
    int r = 0, j = lo;
    for (; j + 4 <= hi; j += 4)
      r += (keys[j] > my) + (keys[j + 1] > my) + (keys[j + 2] > my) + (keys[j + 3] > my);
    for (; j < hi; ++j) r += (keys[j] > my);
    rpart[t] = (u32)r;
  }
  __syncthreads();
  if (t < CPB) {
    const int c = blk * CPB + t;
    if (c < (int)cnt) {
      int rank = 0;
#pragma unroll
      for (int q = 0; q < 8; ++q) rank += (int)rpart[t + 32 * q];
      if (rank < TOPK) {
        u64 my = keys[c];
        float lx = __uint_as_float((u32)(my >> 32));
        float sc = (float)(1.0 / (1.0 + exp(-(double)lx)));   // f64 sigmoid, round once
        u32 idx = ~((u32)my);
        float4 box;
        float kv[10];
        int p, xq, yq;
        float st;
        const float *bb, *kp;
        if (idx < N8) {
          st = 8.f;  p = (int)idx;              xq = p % 480; yq = p / 480; bb = bb8;  kp = kp8;
        } else if (idx < N8 + N16) {
          st = 16.f; p = (int)idx - N8;         xq = p % 240; yq = p / 240; bb = bb16; kp = kp16;
        } else {
          st = 32.f; p = (int)idx - (N8 + N16); xq = p % 120; yq = p / 120; bb = bb32; kp = kp32;
        }
        float cx = (float)xq * st, cy = (float)yq * st;
        {
#pragma clang fp contract(off)
          float d0 = bb[4 * p + 0] * st;
          float d1 = bb[4 * p + 1] * st;
          float d2 = bb[4 * p + 2] * st;
          float d3 = bb[4 * p + 3] * st;
          box.x = cx - d0; box.y = cy - d1; box.z = cx + d2; box.w = cy + d3;
          for (int q = 0; q < 10; ++q)
            kv[q] = kp[10 * p + q] * st + ((q & 1) ? cy : cx);
        }
        ((float4*)out)[rank] = box;
        out[4000 + rank] = sc;
#pragma unroll
        for (int q = 0; q < 10; ++q) out[5000 + 10 * rank + q] = kv[q];
      }
    } else if (c < TOPK) {        // unfilled rows: zero
      ((float4*)out)[c] = make_float4(0.f, 0.f, 0.f, 0.f);
      out[4000 + c] = 0.f;
#pragma unroll
      for (int q = 0; q < 10; ++q) out[5000 + 10 * c + q] = 0.f;
    }
  }
}

// K6: 63 blocks: suppression bitmask (transposed, coalesced) + nz row flags.
__global__ void __launch_bounds__(256) k6_iou(
    const float* __restrict__ out, u64* __restrict__ mask, u64* __restrict__ nz) {
  __shared__ __align__(16) float4 boxes[TOPK];
  const int t = threadIdx.x, blk = blockIdx.x;
  for (int r = t; r < TOPK; r += 256) boxes[r] = ((const float4*)out)[r];
  __syncthreads();
  int task = blk * 256 + t;
  if (task < IOU_TASKS) {
    int w = task / 1000;          // 0..15  (wave-mostly-uniform)
    int i = task - w * 1000;      // 0..999 (consecutive per lane -> coalesced)
    float4 a = boxes[i];
    int bse = w * 64;
    int jend = (bse + 64) < TOPK ? (bse + 64) : TOPK;
    u64 bits = 0;
    for (int j = bse; j < jend; ++j)
      if (j > i && iou_gt04(a, boxes[j])) bits |= 1ull << (j - bse);
    mask[(u64)w * 1000 + i] = bits;
    if (bits) atomicOr(&nz[i >> 6], 1ull << (i & 63));
  }
}

// K7: one block: exact greedy NMS over nonzero-mask rows + suppressed-row zeroing.
__global__ void __launch_bounds__(256) k7_nms(
    const u32* __restrict__ meta, const u64* __restrict__ nzWords,
    const u64* __restrict__ mask, float* __restrict__ out) {
  __shared__ __align__(16) char smem[36864];
  __shared__ u32 sPc[16], sOff17[17];
  __shared__ u64 sRem[NWORDS];
  const int t = threadIdx.x;
  u32 cc = meta[MI_CNT];
  if (cc > LIST_CAP) cc = LIST_CAP;
  const u32 vcnt = cc < TOPK ? cc : TOPK;
  u32* rows = (u32*)smem;               // up to 1000 row ids (4 KB)
  u64* cache = (u64*)(smem + 4096);     // NMS_CACHE x 16 u64 (32 KB)
  u64 nzv = 0;
  if (t < NWORDS) {
    nzv = nzWords[t] & valid_word(t, vcnt);
    sPc[t] = (u32)__popcll(nzv);
  }
  __syncthreads();
  if (t == 0) {
    u32 o = 0;
    for (int w = 0; w < NWORDS; ++w) { sOff17[w] = o; o += sPc[w]; }
    sOff17[16] = o;
  }
  __syncthreads();
  if (t < NWORDS) {                     // expand to ascending row list
    u64 m = nzv;
    u32 o = sOff17[t];
    while (m) { int b = __builtin_ctzll(m); m &= m - 1; rows[o++] = (u32)(t * 64 + b); }
  }
  __syncthreads();
  const int S = (int)sOff17[16];
  const int Sc = S < NMS_CACHE ? S : NMS_CACHE;
  for (int idx = t; idx < Sc * NWORDS; idx += 256) {   // parallel mask prefetch
    int s = idx >> 4, w = idx & 15;
    cache[s * NWORDS + w] = mask[(u64)w * 1000 + rows[s]];
  }
  __syncthreads();
  if (t < 64) {                 // serial greedy chain; lane<16 owns word `lane`
    u64 remv = 0;
    for (int s = 0; s < S; ++s) {
      u32 row = rows[s];
      int c = (int)(row >> 6), b = (int)(row & 63);
      u64 remc = __shfl(remv, c);
      if (!((remc >> b) & 1ull)) {     // row alive -> apply its suppression row
        u64 m = 0;
        if (t < NWORDS)
          m = (s < NMS_CACHE) ? cache[s * NWORDS + t] : mask[(u64)t * 1000 + row];
        remv |= m;
      }
    }
    if (t < NWORDS) sRem[t] = valid_word(t, vcnt) & remv;
  }
  __syncthreads();
  for (int r = t; r < TOPK; r += 256) {
    if ((sRem[r >> 6] >> (r & 63)) & 1ull) {
      ((float4*)out)[r] = make_float4(0.f, 0.f, 0.f, 0.f);
      out[4000 + r] = 0.f;
#pragma unroll
      for (int q = 0; q < 10; ++q) out[5000 + 10 * r + q] = 0.f;
    }
  }
}

extern "C" void kernel_launch(void* const* d_in, const int* in_sizes, int n_in,
                              void* d_out, int out_size, void* d_ws, size_t ws_size,
                              hipStream_t stream) {
  const float* s8   = (const float*)d_in[1];
  const float* bb8  = (const float*)d_in[2];
  const float* kp8  = (const float*)d_in[3];
  const float* s16  = (const float*)d_in[4];
  const float* bb16 = (const float*)d_in[5];
  const float* kp16 = (const float*)d_in[6];
  const float* s32  = (const float*)d_in[7];
  const float* bb32 = (const float*)d_in[8];
  const float* kp32 = (const float*)d_in[9];

  char* ws = (char*)d_ws;
  u32* part    = (u32*)(ws + OFF_PART);
  u32* red     = (u32*)(ws + OFF_RED);
  u32* meta    = (u32*)(ws + OFF_META);
  u64* nzWords = (u64*)(ws + OFF_NZ);
  u64* list    = (u64*)(ws + OFF_LIST);
  u64* mask    = (u64*)(ws + OFF_MASK);
  float* out   = (float*)d_out;

  k1_hist<<<HIST_BLKS, 256, 0, stream>>>(s8, s16, s32, part, meta, nzWords);
  k2_reduce<<<RED_BLKS, 256, 0, stream>>>(part, red);
  k3_findb<<<1, 256, 0, stream>>>(red, meta);
  k4_compact<<<HIST_BLKS, 256, 0, stream>>>(s8, s16, s32, meta, list);
  k5_rank<<<RANK_BLKS, 256, 0, stream>>>(meta, list, bb8, kp8, bb16, kp16, bb32, kp32, out);
  k6_iou<<<IOU_BLKS, 256, 0, stream>>>(out, mask, nzWords);
  k7_nms<<<1, 256, 0, stream>>>(meta, nzWords, mask, out);
}

// Round 6
// 170.596 us; speedup vs baseline: 1.1651x; 1.0431x over previous
//
#include <hip/hip_runtime.h>
#include <stdint.h>

typedef unsigned int u32;
typedef unsigned long long u64;

#define N8   130560   // (2176/8)*(3840/8)   = 272*480
#define N16  32640    // (2176/16)*(3840/16) = 136*240
#define N32  8160     // (2176/32)*(3840/32) = 68*120
#define NTOT 171360
#define NTOT4 42840   // NTOT/4
#define TOPK 1000
#define NWORDS 16
#define NBINS 4096
#define BUCKET_SCALE 682.0f
#define LIST_CAP 2016      // 63*32
#define CPB 32             // candidates ranked per block
#define HIST_BLKS 84       // 84*512 threads = 43008 >= NTOT4
#define HIST_THR 512
#define RED_BLKS 32
#define CMP_BLKS 168       // ceil(NTOT4/256)
#define RANK_BLKS 63
#define IOU_BLKS 63
#define IOU_TASKS (TOPK * NWORDS)   // 16000
#define NMS_CACHE 256
#define POISON 0xAAAAAAAAu

// R14: trim boundaries, keep the no-spin structure (R13 postmortem: dispatch count
// anti-correlates with time across 1/2/3/7-dispatch datapoints -> boundaries ~4-5us,
// spin fabric was the real cost). Cuts: (1) k3 dropped — every k4 block computes B
// from red[] itself (parallel redundant 16KB read + LDS suffix scan); (2) k6+k7
// merged via the R0-proven last-arriver pattern (arrive-and-EXIT, no spin; mask/nz
// via sc1 + syncthreads-drain + arrive-RMW); (3) k1 -> 84x512 halves partial-hist
// traffic (per-block bin count <= 2048 still fits u16). 5 dispatches total.

#define MI_CNT 0       // k4 list-count RMW line
#define MI_IOU 128     // k67 arrive ctr (own 512B line)
#define META_U32 256

// workspace layout (bytes)
#define OFF_PART 0                  // u32[84*2048] u16-pair packed partial hist
#define OFF_RED  688128             // u32[4096]
#define OFF_META 704512             // u32[256]
#define OFF_NZ   705536             // u64[16]
#define OFF_LIST 705664             // u64[2016]
#define OFF_MASK 721792             // u64[16*1000] transposed: mask[w*1000+i]

__device__ __forceinline__ u32 ald32(const u32* p) {
  return __hip_atomic_load(p, __ATOMIC_RELAXED, __HIP_MEMORY_SCOPE_AGENT);
}
__device__ __forceinline__ u64 ald64(const u64* p) {
  return __hip_atomic_load(p, __ATOMIC_RELAXED, __HIP_MEMORY_SCOPE_AGENT);
}
__device__ __forceinline__ void ast64(u64* p, u64 v) {
  __hip_atomic_store(p, v, __ATOMIC_RELAXED, __HIP_MEMORY_SCOPE_AGENT);
}

__device__ __forceinline__ u32 bucket_of(float x) {
  u32 b = (u32)(x * BUCKET_SCALE);
  return b > (NBINS - 1) ? (NBINS - 1) : b;
}

__device__ __forceinline__ float4 load_logit4(int v, const float* s8, const float* s16,
                                              const float* s32) {
  int e = v * 4;
  if (e < N8) return ((const float4*)s8)[v];
  if (e < N8 + N16) return ((const float4*)s16)[v - N8 / 4];
  return ((const float4*)s32)[v - (N8 + N16) / 4];
}

__device__ __forceinline__ bool iou_gt04(float4 a, float4 b) {
#pragma clang fp contract(off)
  float areaA = (a.z - a.x) * (a.w - a.y);
  float areaB = (b.z - b.x) * (b.w - b.y);
  float ltx = fmaxf(a.x, b.x);
  float lty = fmaxf(a.y, b.y);
  float rbx = fminf(a.z, b.z);
  float rby = fminf(a.w, b.w);
  float wx = rbx - ltx; wx = wx > 0.0f ? wx : 0.0f;
  float wy = rby - lty; wy = wy > 0.0f ? wy : 0.0f;
  float inter = wx * wy;
  float un = areaA + areaB - inter;
  un = un > 1e-9f ? un : 1e-9f;
  return (inter / un) > 0.4f;
}

__device__ __forceinline__ u64 valid_word(int w, u32 vcnt) {
  int lo = w * 64;
  if ((int)vcnt >= lo + 64) return ~0ull;
  if ((int)vcnt <= lo) return 0ull;
  return (1ull << (vcnt - (u32)lo)) - 1ull;
}

// K1: 84x512 LDS histogram -> u16-packed partials. blk0 zeroes meta+nz.
__global__ void __launch_bounds__(HIST_THR) k1_hist(
    const float* __restrict__ s8, const float* __restrict__ s16, const float* __restrict__ s32,
    u32* __restrict__ part, u32* __restrict__ meta, u64* __restrict__ nz) {
  __shared__ u32 lh[NBINS];
  const int t = threadIdx.x, blk = blockIdx.x;
#pragma unroll
  for (int k = 0; k < 8; ++k) lh[k * HIST_THR + t] = 0;
  __syncthreads();
  int v = blk * HIST_THR + t;
  if (v < NTOT4) {
    float4 x = load_logit4(v, s8, s16, s32);
    if (x.x > 0.0f) atomicAdd(&lh[bucket_of(x.x)], 1u);
    if (x.y > 0.0f) atomicAdd(&lh[bucket_of(x.y)], 1u);
    if (x.z > 0.0f) atomicAdd(&lh[bucket_of(x.z)], 1u);
    if (x.w > 0.0f) atomicAdd(&lh[bucket_of(x.w)], 1u);
  }
  __syncthreads();
#pragma unroll
  for (int k = 0; k < 4; ++k) {             // per-block bin count <= 2048 -> u16 ok
    int w = k * HIST_THR + t;
    part[blk * 2048 + w] = lh[2 * w] | (lh[2 * w + 1] << 16);
  }
  if (blk == 0) {
    if (t < META_U32) meta[t] = 0;
    if (t < NWORDS) nz[t] = 0ull;
  }
}

// K2: 32 blocks x 128 bins: reduce the 84 packed partials -> red[4096].
__global__ void __launch_bounds__(256) k2_reduce(
    const u32* __restrict__ part, u32* __restrict__ red) {
  __shared__ u32 llo[256], lhi[256];
  const int t = threadIdx.x, blk = blockIdx.x;
  const int w = t & 63, pp = t >> 6;        // word-in-slice, partial-stream
  u32 lo = 0, hi = 0;
  for (int p = pp; p < HIST_BLKS; p += 4) {
    u32 pv = part[p * 2048 + blk * 64 + w];
    lo += pv & 0xFFFFu; hi += pv >> 16;
  }
  llo[t] = lo; lhi[t] = hi;
  __syncthreads();
  if (t < 64) {
    u32 l = llo[t] + llo[64 + t] + llo[128 + t] + llo[192 + t];
    u32 h = lhi[t] + lhi[64 + t] + lhi[128 + t] + lhi[192 + t];
    red[blk * 128 + 2 * t] = l;
    red[blk * 128 + 2 * t + 1] = h;
  }
}

// K4': every block computes B from red (redundant, parallel) then compacts.
__global__ void __launch_bounds__(256) k4_compact(
    const float* __restrict__ s8, const float* __restrict__ s16, const float* __restrict__ s32,
    const u32* __restrict__ red, u32* __restrict__ meta, u64* __restrict__ list) {
  __shared__ u32 hloc[NBINS];               // 16 KB
  __shared__ u32 csum[256];
  __shared__ u32 sB, sBase;
  __shared__ u32 cnt16[16];
  const int t = threadIdx.x, blk = blockIdx.x;
  const int wave = t >> 6, lane = t & 63;
  const int v = blk * 256 + t;
  // prefetch scores while the scan happens
  float4 x = make_float4(-1.f, -1.f, -1.f, -1.f);
  if (v < NTOT4) x = load_logit4(v, s8, s16, s32);
  // ---- inline findB (was k3): suffix-scan red in LDS ----
#pragma unroll
  for (int k = 0; k < 16; ++k) hloc[k * 256 + t] = red[k * 256 + t];
  __syncthreads();
  u32 sum = 0;
  int base = t * 16;
#pragma unroll
  for (int k = 0; k < 16; ++k) sum += hloc[base + k];
  csum[t] = sum;
  __syncthreads();
  for (int off = 1; off < 256; off <<= 1) {   // inclusive suffix scan
    u32 add = (t + off < 256) ? csum[t + off] : 0u;
    __syncthreads();
    csum[t] += add;
    __syncthreads();
  }
  u32 above = (t < 255) ? csum[t + 1] : 0u;
  if (t == 0 && csum[0] < TOPK) sB = 0u;      // fewer than TOPK positives
  if (csum[t] >= TOPK && above < TOPK) {      // exactly one thread
    u32 cum = above, Bv = (u32)(t * 16);
    for (int b = t * 16 + 15; b >= t * 16; --b) {
      cum += hloc[b];
      if (cum >= TOPK) { Bv = (u32)b; break; }
    }
    sB = Bv;
  }
  __syncthreads();
  // ---- compact ----
  const u32 B = sB;
  float c[4] = {x.x, x.y, x.z, x.w};
  u32 win = 0;
#pragma unroll
  for (int j = 0; j < 4; ++j)
    if (c[j] > 0.0f && bucket_of(c[j]) >= B) win |= 1u << j;
  u32 wpos[4], wcnt[4];
#pragma unroll
  for (int j = 0; j < 4; ++j) {
    u64 bal = __ballot((win >> j) & 1u);
    wcnt[j] = (u32)__popcll(bal);
    wpos[j] = (u32)__popcll(bal & ((1ull << lane) - 1ull));
  }
  if (lane == 0) {
#pragma unroll
    for (int j = 0; j < 4; ++j) cnt16[wave * 4 + j] = wcnt[j];
  }
  __syncthreads();
  if (t == 0) {                       // ONE device-atomic RMW per block
    u32 tot = 0, pre[16];
#pragma unroll
    for (int k = 0; k < 16; ++k) { pre[k] = tot; tot += cnt16[k]; }
#pragma unroll
    for (int k = 0; k < 16; ++k) cnt16[k] = pre[k];
    sBase = tot ? atomicAdd(&meta[MI_CNT], tot) : 0u;
  }
  __syncthreads();
#pragma unroll
  for (int j = 0; j < 4; ++j) {
    if ((win >> j) & 1u) {
      u32 dst = sBase + cnt16[wave * 4 + j] + wpos[j];
      if (dst < LIST_CAP) {
        u32 idx = (u32)(v * 4 + j);
        list[dst] = ((u64)__float_as_uint(c[j]) << 32) | (u64)(~idx);
      }
    }
  }
}

// K5: 63 blocks: exact rank (8 key-slices per candidate) + decode -> out.
__global__ void __launch_bounds__(256) k5_rank(
    const u32* __restrict__ meta, const u64* __restrict__ list,
    const float* __restrict__ bb8,  const float* __restrict__ kp8,
    const float* __restrict__ bb16, const float* __restrict__ kp16,
    const float* __restrict__ bb32, const float* __restrict__ kp32,
    float* __restrict__ out) {
  __shared__ __align__(16) u64 keys[LIST_CAP];
  __shared__ u32 rpart[256];
  __shared__ u32 sCnt;
  const int t = threadIdx.x, blk = blockIdx.x;
  if (t == 0) { u32 cc = meta[MI_CNT]; sCnt = cc > LIST_CAP ? LIST_CAP : cc; }
  __syncthreads();
  const u32 cnt = sCnt;
  for (int j = t; j < LIST_CAP; j += 256) keys[j] = (j < (int)cnt) ? list[j] : 0ull;
  __syncthreads();
  {
    const int ci = t & 31, sl = t >> 5;       // candidate-in-block, key-slice
    const int c = blk * CPB + ci;
    const int chunk = ((int)cnt + 7) >> 3;
    int lo = sl * chunk; if (lo > (int)cnt) lo = (int)cnt;
    int hi = lo + chunk; if (hi > (int)cnt) hi = (int)cnt;
    u64 my = keys[c];
    int r = 0, j = lo;
    for (; j + 4 <= hi; j += 4)
      r += (keys[j] > my) + (keys[j + 1] > my) + (keys[j + 2] > my) + (keys[j + 3] > my);
    for (; j < hi; ++j) r += (keys[j] > my);
    rpart[t] = (u32)r;
  }
  __syncthreads();
  if (t < CPB) {
    const int c = blk * CPB + t;
    if (c < (int)cnt) {
      int rank = 0;
#pragma unroll
      for (int q = 0; q < 8; ++q) rank += (int)rpart[t + 32 * q];
      if (rank < TOPK) {
        u64 my = keys[c];
        float lx = __uint_as_float((u32)(my >> 32));
        float sc = (float)(1.0 / (1.0 + exp(-(double)lx)));   // f64 sigmoid, round once
        u32 idx = ~((u32)my);
        float4 box;
        float kv[10];
        int p, xq, yq;
        float st;
        const float *bb, *kp;
        if (idx < N8) {
          st = 8.f;  p = (int)idx;              xq = p % 480; yq = p / 480; bb = bb8;  kp = kp8;
        } else if (idx < N8 + N16) {
          st = 16.f; p = (int)idx - N8;         xq = p % 240; yq = p / 240; bb = bb16; kp = kp16;
        } else {
          st = 32.f; p = (int)idx - (N8 + N16); xq = p % 120; yq = p / 120; bb = bb32; kp = kp32;
        }
        float cx = (float)xq * st, cy = (float)yq * st;
        {
#pragma clang fp contract(off)
          float d0 = bb[4 * p + 0] * st;
          float d1 = bb[4 * p + 1] * st;
          float d2 = bb[4 * p + 2] * st;
          float d3 = bb[4 * p + 3] * st;
          box.x = cx - d0; box.y = cy - d1; box.z = cx + d2; box.w = cy + d3;
          for (int q = 0; q < 10; ++q)
            kv[q] = kp[10 * p + q] * st + ((q & 1) ? cy : cx);
        }
        ((float4*)out)[rank] = box;
        out[4000 + rank] = sc;
#pragma unroll
        for (int q = 0; q < 10; ++q) out[5000 + 10 * rank + q] = kv[q];
      }
    } else if (c < TOPK) {        // unfilled rows: zero
      ((float4*)out)[c] = make_float4(0.f, 0.f, 0.f, 0.f);
      out[4000 + c] = 0.f;
#pragma unroll
      for (int q = 0; q < 10; ++q) out[5000 + 10 * c + q] = 0.f;
    }
  }
}

// K67: suppression bitmask (63 blocks, sc1 stores) + last-arriver greedy NMS.
// Last-arriver pattern (R0-proven): non-last blocks arrive and EXIT — no spinning.
__global__ void __launch_bounds__(256) k67_iou_nms(
    u32* meta, u64* nzWords, u64* mask, float* out) {
  __shared__ __align__(16) char smem[36864];
  __shared__ int isLast;
  __shared__ u32 sPc[16], sOff17[17];
  __shared__ u64 sRem[NWORDS];
  const int t = threadIdx.x, blk = blockIdx.x;

  float4* boxes = (float4*)smem;
  for (int r = t; r < TOPK; r += 256) boxes[r] = ((const float4*)out)[r];
  __syncthreads();
  int task = blk * 256 + t;
  if (task < IOU_TASKS) {
    int w = task / 1000;          // 0..15  (wave-mostly-uniform)
    int i = task - w * 1000;      // 0..999 (consecutive per lane -> coalesced)
    float4 a = boxes[i];
    int bse = w * 64;
    int jend = (bse + 64) < TOPK ? (bse + 64) : TOPK;
    u64 bits = 0;
    for (int j = bse; j < jend; ++j)          // boxes[j] wave-broadcast
      if (j > i && iou_gt04(a, boxes[j])) bits |= 1ull << (j - bse);
    ast64(&mask[(u64)w * 1000 + i], bits);    // sc1: visible to the last arriver
    if (bits) atomicOr(&nzWords[i >> 6], 1ull << (i & 63));
  }
  __syncthreads();                // drain sc1 mask stores + atomics (vmcnt)
  if (t == 0)
    isLast = (__hip_atomic_fetch_add(&meta[MI_IOU], 1u, __ATOMIC_RELAXED,
                                     __HIP_MEMORY_SCOPE_AGENT) == (u32)(IOU_BLKS - 1));
  __syncthreads();
  if (!isLast) return;

  // ---- last arriver: exact greedy NMS over nonzero-mask rows only ----
  u32 cc = meta[MI_CNT];
  if (cc > LIST_CAP) cc = LIST_CAP;
  const u32 vcnt = cc < TOPK ? cc : TOPK;
  u32* rows = (u32*)smem;               // up to 1000 row ids (4 KB)
  u64* cache = (u64*)(smem + 4096);     // NMS_CACHE x 16 u64 (32 KB)
  u64 nzv = 0;
  if (t < NWORDS) {
    nzv = ald64(&nzWords[t]) & valid_word(t, vcnt);
    sPc[t] = (u32)__popcll(nzv);
  }
  __syncthreads();
  if (t == 0) {
    u32 o = 0;
    for (int w = 0; w < NWORDS; ++w) { sOff17[w] = o; o += sPc[w]; }
    sOff17[16] = o;
  }
  __syncthreads();
  if (t < NWORDS) {                     // expand to ascending row list
    u64 m = nzv;
    u32 o = sOff17[t];
    while (m) { int b = __builtin_ctzll(m); m &= m - 1; rows[o++] = (u32)(t * 64 + b); }
  }
  __syncthreads();
  const int S = (int)sOff17[16];
  const int Sc = S < NMS_CACHE ? S : NMS_CACHE;
  for (int idx = t; idx < Sc * NWORDS; idx += 256) {   // parallel mask prefetch
    int s = idx >> 4, w = idx & 15;
    cache[s * NWORDS + w] = ald64(&mask[(u64)w * 1000 + rows[s]]);
  }
  __syncthreads();
  if (t < 64) {                 // serial greedy chain; lane<16 owns word `lane`
    u64 remv = 0;
    for (int s = 0; s < S; ++s) {
      u32 row = rows[s];
      int c = (int)(row >> 6), b = (int)(row & 63);
      u64 remc = __shfl(remv, c);
      if (!((remc >> b) & 1ull)) {     // row alive -> apply its suppression row
        u64 m = 0;
        if (t < NWORDS)
          m = (s < NMS_CACHE) ? cache[s * NWORDS + t] : ald64(&mask[(u64)t * 1000 + row]);
        remv |= m;
      }
    }
    if (t < NWORDS) sRem[t] = valid_word(t, vcnt) & remv;
  }
  __syncthreads();
  for (int r = t; r < TOPK; r += 256) {
    if ((sRem[r >> 6] >> (r & 63)) & 1ull) {
      ((float4*)out)[r] = make_float4(0.f, 0.f, 0.f, 0.f);
      out[4000 + r] = 0.f;
#pragma unroll
      for (int q = 0; q < 10; ++q) out[5000 + 10 * r + q] = 0.f;
    }
  }
}

extern "C" void kernel_launch(void* const* d_in, const int* in_sizes, int n_in,
                              void* d_out, int out_size, void* d_ws, size_t ws_size,
                              hipStream_t stream) {
  const float* s8   = (const float*)d_in[1];
  const float* bb8  = (const float*)d_in[2];
  const float* kp8  = (const float*)d_in[3];
  const float* s16  = (const float*)d_in[4];
  const float* bb16 = (const float*)d_in[5];
  const float* kp16 = (const float*)d_in[6];
  const float* s32  = (const float*)d_in[7];
  const float* bb32 = (const float*)d_in[8];
  const float* kp32 = (const float*)d_in[9];

  char* ws = (char*)d_ws;
  u32* part    = (u32*)(ws + OFF_PART);
  u32* red     = (u32*)(ws + OFF_RED);
  u32* meta    = (u32*)(ws + OFF_META);
  u64* nzWords = (u64*)(ws + OFF_NZ);
  u64* list    = (u64*)(ws + OFF_LIST);
  u64* mask    = (u64*)(ws + OFF_MASK);
  float* out   = (float*)d_out;

  k1_hist<<<HIST_BLKS, HIST_THR, 0, stream>>>(s8, s16, s32, part, meta, nzWords);
  k2_reduce<<<RED_BLKS, 256, 0, stream>>>(part, red);
  k4_compact<<<CMP_BLKS, 256, 0, stream>>>(s8, s16, s32, red, meta, list);
  k5_rank<<<RANK_BLKS, 256, 0, stream>>>(meta, list, bb8, kp8, bb16, kp16, bb32, kp32, out);
  k67_iou_nms<<<IOU_BLKS, 256, 0, stream>>>(meta, nzWords, mask, out);
}

// Round 7
// 169.685 us; speedup vs baseline: 1.1714x; 1.0054x over previous
//
#include <hip/hip_runtime.h>
#include <stdint.h>

typedef unsigned int u32;
typedef unsigned long long u64;

#define N8   130560   // (2176/8)*(3840/8)   = 272*480
#define N16  32640    // (2176/16)*(3840/16) = 136*240
#define N32  8160     // (2176/32)*(3840/32) = 68*120
#define NTOT 171360
#define NTOT4 42840   // NTOT/4
#define TOPK 1000
#define NWORDS 16
#define NBINS 512          // R15: 512 bins (was 4096). Threshold granularity ~0.012
                           // logit -> ~34 expected extra candidates; LIST_CAP ample.
#define BUCKET_SCALE 85.25f   // 682/8, same logit range as before
#define LIST_CAP 2016      // 63*32
#define CPB 32             // candidates ranked per block
#define HIST_BLKS 84       // 84*512 threads = 43008 >= NTOT4
#define HIST_THR 512
#define CMP_BLKS 168       // ceil(NTOT4/256)
#define RANK_BLKS 63
#define IOU_BLKS 63
#define IOU_TASKS (TOPK * NWORDS)   // 16000
#define NMS_CACHE 256
#define POISON 0xAAAAAAAAu

// R15: 4 dispatches, still zero spins (R13/R14 postmortems: boundaries ~3us, spin
// fabric was the real cost; structure validated twice). Cuts vs R14:
// (1) NBINS 4096->512: partials shrink 8x (84x256 packed u32 = 86KB);
// (2) k2 ELIMINATED: k1's LAST ARRIVER (arrive-and-exit, not a spin) reduces the
//     84 partials + suffix-scans 512 bins + plain-stores B to a dedicated,
//     never-zeroed 512B line (two-dirty-L2-copy hazard avoided);
// (3) k4 drops its per-block findB (reads the single B word instead).
// Handoffs: sc1 stores + __syncthreads vmcnt-drain + arrive-RMW (R6-R8 pattern);
// k1's arrive counter is poison-tolerant (normc) + self-resetting since it cannot
// be pre-zeroed within the same dispatch.

#define MI_CNT 0       // line 0: k4 list-count RMW (zeroed by k1 blk0)
#define MI_IOU 128     // line 1: k67 arrive ctr   (zeroed by k1 blk0)
#define MI_ARR 256     // line 2: k1 arrive ctr    (NEVER zeroed; normc+self-reset)
#define MI_B   384     // line 3: B value          (NEVER zeroed; plain-written once)
#define META_U32 512
#define META_ZERO 256  // k1 blk0 zeroes only lines 0-1

// workspace layout (bytes)
#define OFF_PART 0                  // u32[84*256] u16-pair packed partial hist
#define OFF_META 86016              // u32[512]
#define OFF_NZ   88064              // u64[16]
#define OFF_LIST 88192              // u64[2016]
#define OFF_MASK 104320             // u64[16*1000] transposed: mask[w*1000+i]

__device__ __forceinline__ u32 ald32(const u32* p) {
  return __hip_atomic_load(p, __ATOMIC_RELAXED, __HIP_MEMORY_SCOPE_AGENT);
}
__device__ __forceinline__ u64 ald64(const u64* p) {
  return __hip_atomic_load(p, __ATOMIC_RELAXED, __HIP_MEMORY_SCOPE_AGENT);
}
__device__ __forceinline__ void ast32(u32* p, u32 v) {
  __hip_atomic_store(p, v, __ATOMIC_RELAXED, __HIP_MEMORY_SCOPE_AGENT);
}
__device__ __forceinline__ void ast64(u64* p, u64 v) {
  __hip_atomic_store(p, v, __ATOMIC_RELAXED, __HIP_MEMORY_SCOPE_AGENT);
}
__device__ __forceinline__ u32 normc(u32 v) {   // tolerate 0xAAAAAAAA poison base
  return v >= 0x80000000u ? v - POISON : v;
}
// true for the LAST arriver; self-resets for the next launch
__device__ __forceinline__ bool arrive_last(u32* p, u32 total) {
  u32 old = __hip_atomic_fetch_add(p, 1u, __ATOMIC_RELAXED, __HIP_MEMORY_SCOPE_AGENT);
  if (normc(old) == total - 1u) { ast32(p, 0u); return true; }
  return false;
}

__device__ __forceinline__ u32 bucket_of(float x) {
  u32 b = (u32)(x * BUCKET_SCALE);
  return b > (NBINS - 1) ? (NBINS - 1) : b;
}

__device__ __forceinline__ float4 load_logit4(int v, const float* s8, const float* s16,
                                              const float* s32) {
  int e = v * 4;
  if (e < N8) return ((const float4*)s8)[v];
  if (e < N8 + N16) return ((const float4*)s16)[v - N8 / 4];
  return ((const float4*)s32)[v - (N8 + N16) / 4];
}

__device__ __forceinline__ bool iou_gt04(float4 a, float4 b) {
#pragma clang fp contract(off)
  float areaA = (a.z - a.x) * (a.w - a.y);
  float areaB = (b.z - b.x) * (b.w - b.y);
  float ltx = fmaxf(a.x, b.x);
  float lty = fmaxf(a.y, b.y);
  float rbx = fminf(a.z, b.z);
  float rby = fminf(a.w, b.w);
  float wx = rbx - ltx; wx = wx > 0.0f ? wx : 0.0f;
  float wy = rby - lty; wy = wy > 0.0f ? wy : 0.0f;
  float inter = wx * wy;
  float un = areaA + areaB - inter;
  un = un > 1e-9f ? un : 1e-9f;
  return (inter / un) > 0.4f;
}

__device__ __forceinline__ u64 valid_word(int w, u32 vcnt) {
  int lo = w * 64;
  if ((int)vcnt >= lo + 64) return ~0ull;
  if ((int)vcnt <= lo) return 0ull;
  return (1ull << (vcnt - (u32)lo)) - 1ull;
}

// K1: 84x512 LDS 512-bin histogram -> sc1 packed partial; last arriver reduces
// all partials, suffix-scans, and writes B. blk0 zeroes meta lines 0-1 + nz.
__global__ void __launch_bounds__(HIST_THR) k1_hist(
    const float* __restrict__ s8, const float* __restrict__ s16, const float* __restrict__ s32,
    u32* __restrict__ part, u32* meta, u64* __restrict__ nz) {
  __shared__ u32 lh[NBINS];       // histogram, then reused as global bins
  __shared__ u32 csum[256];
  __shared__ int sLast;
  const int t = threadIdx.x, blk = blockIdx.x;
  lh[t < NBINS ? t : 0] = 0;      // HIST_THR==512==NBINS: thread t inits bin t
  __syncthreads();
  int v = blk * HIST_THR + t;
  if (v < NTOT4) {
    float4 x = load_logit4(v, s8, s16, s32);
    if (x.x > 0.0f) atomicAdd(&lh[bucket_of(x.x)], 1u);
    if (x.y > 0.0f) atomicAdd(&lh[bucket_of(x.y)], 1u);
    if (x.z > 0.0f) atomicAdd(&lh[bucket_of(x.z)], 1u);
    if (x.w > 0.0f) atomicAdd(&lh[bucket_of(x.w)], 1u);
  }
  __syncthreads();
  if (t < 256)                    // per-block bin count <= 2048 -> u16 ok
    ast32(&part[blk * 256 + t], lh[2 * t] | (lh[2 * t + 1] << 16));
  if (blk == 0) {
    if (t < META_ZERO) meta[t] = 0;          // lines 0-1 only (plain, boundary-coherent)
    if (t < NWORDS) nz[t] = 0ull;
  }
  __syncthreads();                // drain sc1 partial stores (vmcnt)
  if (t == 0) sLast = arrive_last(&meta[MI_ARR], HIST_BLKS) ? 1 : 0;
  __syncthreads();
  if (!sLast) return;

  // ---- last arriver: reduce 84 partials + suffix-scan + publish B ----
  u32 lo = 0, hi = 0;
  if (t < 256) {
    int p = 0;
    for (; p + 4 <= HIST_BLKS; p += 4) {
      u32 a0 = ald32(&part[(p + 0) * 256 + t]);
      u32 a1 = ald32(&part[(p + 1) * 256 + t]);
      u32 a2 = ald32(&part[(p + 2) * 256 + t]);
      u32 a3 = ald32(&part[(p + 3) * 256 + t]);
      lo += (a0 & 0xFFFFu) + (a1 & 0xFFFFu) + (a2 & 0xFFFFu) + (a3 & 0xFFFFu);
      hi += (a0 >> 16) + (a1 >> 16) + (a2 >> 16) + (a3 >> 16);
    }
    for (; p < HIST_BLKS; ++p) {
      u32 a = ald32(&part[p * 256 + t]);
      lo += a & 0xFFFFu; hi += a >> 16;
    }
  }
  __syncthreads();                // lh no longer needed as histogram
  if (t < 256) { lh[2 * t] = lo; lh[2 * t + 1] = hi; csum[t] = lo + hi; }
  __syncthreads();
  for (int off = 1; off < 256; off <<= 1) {   // inclusive suffix scan (2-bin groups)
    u32 add = (t < 256 && t + off < 256) ? csum[t + off] : 0u;
    __syncthreads();
    if (t < 256) csum[t] += add;
    __syncthreads();
  }
  if (t == 0 && csum[0] < TOPK) meta[MI_B] = 0u;   // fewer than TOPK positives
  if (t < 256) {
    u32 above = (t < 255) ? csum[t + 1] : 0u;
    if (csum[t] >= TOPK && above < TOPK) {         // exactly one thread
      u32 cum = above + lh[2 * t + 1];
      meta[MI_B] = (cum >= TOPK) ? (u32)(2 * t + 1) : (u32)(2 * t);  // plain, own line
    }
  }
}

// K4: block-aggregated compaction of bucket>=B candidates into list (plain stores).
__global__ void __launch_bounds__(256) k4_compact(
    const float* __restrict__ s8, const float* __restrict__ s16, const float* __restrict__ s32,
    u32* __restrict__ meta, u64* __restrict__ list) {
  __shared__ u32 sB, sBase;
  __shared__ u32 cnt16[16];
  const int t = threadIdx.x, blk = blockIdx.x;
  const int wave = t >> 6, lane = t & 63;
  const int v = blk * 256 + t;
  if (t == 0) sB = meta[MI_B];
  float4 x = make_float4(-1.f, -1.f, -1.f, -1.f);
  if (v < NTOT4) x = load_logit4(v, s8, s16, s32);
  __syncthreads();
  const u32 B = sB;
  float c[4] = {x.x, x.y, x.z, x.w};
  u32 win = 0;
#pragma unroll
  for (int j = 0; j < 4; ++j)
    if (c[j] > 0.0f && bucket_of(c[j]) >= B) win |= 1u << j;
  u32 wpos[4], wcnt[4];
#pragma unroll
  for (int j = 0; j < 4; ++j) {
    u64 bal = __ballot((win >> j) & 1u);
    wcnt[j] = (u32)__popcll(bal);
    wpos[j] = (u32)__popcll(bal & ((1ull << lane) - 1ull));
  }
  if (lane == 0) {
#pragma unroll
    for (int j = 0; j < 4; ++j) cnt16[wave * 4 + j] = wcnt[j];
  }
  __syncthreads();
  if (t == 0) {                       // ONE device-atomic RMW per block
    u32 tot = 0, pre[16];
#pragma unroll
    for (int k = 0; k < 16; ++k) { pre[k] = tot; tot += cnt16[k]; }
#pragma unroll
    for (int k = 0; k < 16; ++k) cnt16[k] = pre[k];
    sBase = tot ? atomicAdd(&meta[MI_CNT], tot) : 0u;
  }
  __syncthreads();
#pragma unroll
  for (int j = 0; j < 4; ++j) {
    if ((win >> j) & 1u) {
      u32 dst = sBase + cnt16[wave * 4 + j] + wpos[j];
      if (dst < LIST_CAP) {
        u32 idx = (u32)(v * 4 + j);
        list[dst] = ((u64)__float_as_uint(c[j]) << 32) | (u64)(~idx);
      }
    }
  }
}

// K5: 63 blocks: exact rank (8 key-slices per candidate) + decode -> out.
__global__ void __launch_bounds__(256) k5_rank(
    const u32* __restrict__ meta, const u64* __restrict__ list,
    const float* __restrict__ bb8,  const float* __restrict__ kp8,
    const float* __restrict__ bb16, const float* __restrict__ kp16,
    const float* __restrict__ bb32, const float* __restrict__ kp32,
    float* __restrict__ out) {
  __shared__ __align__(16) u64 keys[LIST_CAP];
  __shared__ u32 rpart[256];
  __shared__ u32 sCnt;
  const int t = threadIdx.x, blk = blockIdx.x;
  if (t == 0) { u32 cc = meta[MI_CNT]; sCnt = cc > LIST_CAP ? LIST_CAP : cc; }
  __syncthreads();
  const u32 cnt = sCnt;
  for (int j = t; j < LIST_CAP; j += 256) keys[j] = (j < (int)cnt) ? list[j] : 0ull;
  __syncthreads();
  {
    const int ci = t & 31, sl = t >> 5;       // candidate-in-block, key-slice
    const int c = blk * CPB + ci;
    const int chunk = ((int)cnt + 7) >> 3;
    int lo = sl * chunk; if (lo > (int)cnt) lo = (int)cnt;
    int hi = lo + chunk; if (hi > (int)cnt) hi = (int)cnt;
    u64 my = keys[c];
    int r = 0, j = lo;
    for (; j + 4 <= hi; j += 4)
      r += (keys[j] > my) + (keys[j + 1] > my) + (keys[j + 2] > my) + (keys[j + 3] > my);
    for (; j < hi; ++j) r += (keys[j] > my);
    rpart[t] = (u32)r;
  }
  __syncthreads();
  if (t < CPB) {
    const int c = blk * CPB + t;
    if (c < (int)cnt) {
      int rank = 0;
#pragma unroll
      for (int q = 0; q < 8; ++q) rank += (int)rpart[t + 32 * q];
      if (rank < TOPK) {
        u64 my = keys[c];
        float lx = __uint_as_float((u32)(my >> 32));
        float sc = (float)(1.0 / (1.0 + exp(-(double)lx)));   // f64 sigmoid, round once
        u32 idx = ~((u32)my);
        float4 box;
        float kv[10];
        int p, xq, yq;
        float st;
        const float *bb, *kp;
        if (idx < N8) {
          st = 8.f;  p = (int)idx;              xq = p % 480; yq = p / 480; bb = bb8;  kp = kp8;
        } else if (idx < N8 + N16) {
          st = 16.f; p = (int)idx - N8;         xq = p % 240; yq = p / 240; bb = bb16; kp = kp16;
        } else {
          st = 32.f; p = (int)idx - (N8 + N16); xq = p % 120; yq = p / 120; bb = bb32; kp = kp32;
        }
        float cx = (float)xq * st, cy = (float)yq * st;
        {
#pragma clang fp contract(off)
          float d0 = bb[4 * p + 0] * st;
          float d1 = bb[4 * p + 1] * st;
          float d2 = bb[4 * p + 2] * st;
          float d3 = bb[4 * p + 3] * st;
          box.x = cx - d0; box.y = cy - d1; box.z = cx + d2; box.w = cy + d3;
          for (int q = 0; q < 10; ++q)
            kv[q] = kp[10 * p + q] * st + ((q & 1) ? cy : cx);
        }
        ((float4*)out)[rank] = box;
        out[4000 + rank] = sc;
#pragma unroll
        for (int q = 0; q < 10; ++q) out[5000 + 10 * rank + q] = kv[q];
      }
    } else if (c < TOPK) {        // unfilled rows: zero
      ((float4*)out)[c] = make_float4(0.f, 0.f, 0.f, 0.f);
      out[4000 + c] = 0.f;
#pragma unroll
      for (int q = 0; q < 10; ++q) out[5000 + 10 * c + q] = 0.f;
    }
  }
}

// K67: suppression bitmask (63 blocks, sc1 stores) + last-arriver greedy NMS.
__global__ void __launch_bounds__(256) k67_iou_nms(
    u32* meta, u64* nzWords, u64* mask, float* out) {
  __shared__ __align__(16) char smem[36864];
  __shared__ int isLast;
  __shared__ u32 sPc[16], sOff17[17];
  __shared__ u64 sRem[NWORDS];
  const int t = threadIdx.x, blk = blockIdx.x;

  float4* boxes = (float4*)smem;
  for (int r = t; r < TOPK; r += 256) boxes[r] = ((const float4*)out)[r];
  __syncthreads();
  int task = blk * 256 + t;
  if (task < IOU_TASKS) {
    int w = task / 1000;          // 0..15  (wave-mostly-uniform)
    int i = task - w * 1000;      // 0..999 (consecutive per lane -> coalesced)
    float4 a = boxes[i];
    int bse = w * 64;
    int jend = (bse + 64) < TOPK ? (bse + 64) : TOPK;
    u64 bits = 0;
    for (int j = bse; j < jend; ++j)          // boxes[j] wave-broadcast
      if (j > i && iou_gt04(a, boxes[j])) bits |= 1ull << (j - bse);
    ast64(&mask[(u64)w * 1000 + i], bits);    // sc1: visible to the last arriver
    if (bits) atomicOr(&nzWords[i >> 6], 1ull << (i & 63));
  }
  __syncthreads();                // drain sc1 mask stores + atomics (vmcnt)
  if (t == 0)
    isLast = (__hip_atomic_fetch_add(&meta[MI_IOU], 1u, __ATOMIC_RELAXED,
                                     __HIP_MEMORY_SCOPE_AGENT) == (u32)(IOU_BLKS - 1));
  __syncthreads();
  if (!isLast) return;

  // ---- last arriver: exact greedy NMS over nonzero-mask rows only ----
  u32 cc = meta[MI_CNT];
  if (cc > LIST_CAP) cc = LIST_CAP;
  const u32 vcnt = cc < TOPK ? cc : TOPK;
  u32* rows = (u32*)smem;               // up to 1000 row ids (4 KB)
  u64* cache = (u64*)(smem + 4096);     // NMS_CACHE x 16 u64 (32 KB)
  u64 nzv = 0;
  if (t < NWORDS) {
    nzv = ald64(&nzWords[t]) & valid_word(t, vcnt);
    sPc[t] = (u32)__popcll(nzv);
  }
  __syncthreads();
  if (t == 0) {
    u32 o = 0;
    for (int w = 0; w < NWORDS; ++w) { sOff17[w] = o; o += sPc[w]; }
    sOff17[16] = o;
  }
  __syncthreads();
  if (t < NWORDS) {                     // expand to ascending row list
    u64 m = nzv;
    u32 o = sOff17[t];
    while (m) { int b = __builtin_ctzll(m); m &= m - 1; rows[o++] = (u32)(t * 64 + b); }
  }
  __syncthreads();
  const int S = (int)sOff17[16];
  const int Sc = S < NMS_CACHE ? S : NMS_CACHE;
  for (int idx = t; idx < Sc * NWORDS; idx += 256) {   // parallel mask prefetch
    int s = idx >> 4, w = idx & 15;
    cache[s * NWORDS + w] = ald64(&mask[(u64)w * 1000 + rows[s]]);
  }
  __syncthreads();
  if (t < 64) {                 // serial greedy chain; lane<16 owns word `lane`
    u64 remv = 0;
    for (int s = 0; s < S; ++s) {
      u32 row = rows[s];
      int c = (int)(row >> 6), b = (int)(row & 63);
      u64 remc = __shfl(remv, c);
      if (!((remc >> b) & 1ull)) {     // row alive -> apply its suppression row
        u64 m = 0;
        if (t < NWORDS)
          m = (s < NMS_CACHE) ? cache[s * NWORDS + t] : ald64(&mask[(u64)t * 1000 + row]);
        remv |= m;
      }
    }
    if (t < NWORDS) sRem[t] = valid_word(t, vcnt) & remv;
  }
  __syncthreads();
  for (int r = t; r < TOPK; r += 256) {
    if ((sRem[r >> 6] >> (r & 63)) & 1ull) {
      ((float4*)out)[r] = make_float4(0.f, 0.f, 0.f, 0.f);
      out[4000 + r] = 0.f;
#pragma unroll
      for (int q = 0; q < 10; ++q) out[5000 + 10 * r + q] = 0.f;
    }
  }
}

extern "C" void kernel_launch(void* const* d_in, const int* in_sizes, int n_in,
                              void* d_out, int out_size, void* d_ws, size_t ws_size,
                              hipStream_t stream) {
  const float* s8   = (const float*)d_in[1];
  const float* bb8  = (const float*)d_in[2];
  const float* kp8  = (const float*)d_in[3];
  const float* s16  = (const float*)d_in[4];
  const float* bb16 = (const float*)d_in[5];
  const float* kp16 = (const float*)d_in[6];
  const float* s32  = (const float*)d_in[7];
  const float* bb32 = (const float*)d_in[8];
  const float* kp32 = (const float*)d_in[9];

  char* ws = (char*)d_ws;
  u32* part    = (u32*)(ws + OFF_PART);
  u32* meta    = (u32*)(ws + OFF_META);
  u64* nzWords = (u64*)(ws + OFF_NZ);
  u64* list    = (u64*)(ws + OFF_LIST);
  u64* mask    = (u64*)(ws + OFF_MASK);
  float* out   = (float*)d_out;

  k1_hist<<<HIST_BLKS, HIST_THR, 0, stream>>>(s8, s16, s32, part, meta, nzWords);
  k4_compact<<<CMP_BLKS, 256, 0, stream>>>(s8, s16, s32, meta, list);
  k5_rank<<<RANK_BLKS, 256, 0, stream>>>(meta, list, bb8, kp8, bb16, kp16, bb32, kp32, out);
  k67_iou_nms<<<IOU_BLKS, 256, 0, stream>>>(meta, nzWords, mask, out);
}